// Round 7
// baseline (6339.717 us; speedup 1.0000x reference)
//
#include <hip/hip_runtime.h>
#include <hip/hip_bf16.h>

// ---------------------------------------------------------------------------
// Problem constants
// ---------------------------------------------------------------------------
#define NA 5000           // atoms
#define NE 40000          // edges
// DA=128, DV=96, DD=64, NL=8, L=2

// ---------------------------------------------------------------------------
// Workspace layout (float indices)
// ---------------------------------------------------------------------------
static const int POFF[13] = {0, 131072, 229376, 294912, 368640, 466944, 516096,
                             589824, 663552, 696320, 761856, 811008, 843776};
#define A_OFF    892928          // a  [2][NA][128] fp32
#define V_OFF    2172928         // v  [2][NA][288] fp32
#define D_OFF    5052928         // d  [2][NA][576] fp32
#define PHI_OFF  10812928        // [NE][12] fp32
#define PSIA_OFF 11292928        // bf16 [NE][256]  -> 5,120,000 floats
#define PSIV_OFF 16412928        // bf16 [NE][576]  -> 11,520,000 floats
#define PSID_OFF 27932928        // bf16 [NE][1152] -> 23,040,000 floats
#define INT_OFF  50972928
// int region (indices into (int*)(ws + INT_OFF))
#define ICNT  0        // [5000]
#define ICUR  5000     // [5000]
#define SCNT  10000    // [5000]
#define SCUR  15000    // [5000]
#define IOFF  20000    // [5001]
#define SOFF  25008    // [5001]
#define IEIDX 30016    // [NE]
#define ISLOT 70016    // [NE]
#define SPERM 110016   // [NE]

// output layout (floats)
#define OUT_V 640000
#define OUT_D 2080000

#define OFF_000 POFF[0]
#define OFF_110 POFF[1]
#define OFF_220 POFF[2]
#define OFF_011 POFF[3]
#define OFF_101 POFF[4]
#define OFF_121 POFF[5]
#define OFF_211 POFF[6]
#define OFF_111 POFF[7]
#define OFF_022 POFF[8]
#define OFF_202 POFF[9]
#define OFF_112 POFF[10]
#define OFF_222 POFF[11]
#define OFF_212 POFF[12]

__device__ __forceinline__ float dot4f(float4 a, float4 b) {
  return a.x*b.x + a.y*b.y + a.z*b.z + a.w*b.w;
}
__device__ __forceinline__ float lrelu(float x) { return x > 0.f ? x : 0.1f*x; }
__device__ __forceinline__ float bf2f(unsigned short u) {
  union { unsigned int i; float f; } x; x.i = ((unsigned int)u) << 16; return x.f;
}
__device__ __forceinline__ unsigned short f2bf(float f) {
  union { unsigned int i; float f; } x; x.f = f;
  unsigned int r = x.i + 0x7FFFu + ((x.i >> 16) & 1u);
  return (unsigned short)(r >> 16);
}

// ---------------------------------------------------------------------------
// P transpose: src [O][8][C] -> dst [C][O][8]
// ---------------------------------------------------------------------------
__global__ __launch_bounds__(256) void transposeP_kernel(
    const float* __restrict__ src, float* __restrict__ dst, int O, int C)
{
  int idx = blockIdx.x * 256 + threadIdx.x;
  if (idx >= O * C) return;
  int o = idx / C, c = idx % C;
#pragma unroll
  for (int k = 0; k < 8; ++k)
    dst[((size_t)c * O + o) * 8 + k] = src[((size_t)o * 8 + k) * C + c];
}

// ---------------------------------------------------------------------------
// Counting sorts
// ---------------------------------------------------------------------------
__global__ __launch_bounds__(256) void hist_kernel(const int* __restrict__ key, int* __restrict__ cnt) {
  int e = blockIdx.x * 256 + threadIdx.x;
  if (e < NE) atomicAdd(&cnt[key[e]], 1);
}

__global__ __launch_bounds__(256) void scan_kernel(const int* __restrict__ cnt, int* __restrict__ off) {
  __shared__ int part[256];
  const int t = threadIdx.x;
  int loc[20]; int s = 0;
#pragma unroll
  for (int i = 0; i < 20; ++i) {
    int idx = t * 20 + i;
    int v = (idx < NA) ? cnt[idx] : 0;
    loc[i] = v; s += v;
  }
  part[t] = s; __syncthreads();
  for (int ofs = 1; ofs < 256; ofs <<= 1) {
    int v = (t >= ofs) ? part[t - ofs] : 0;
    __syncthreads();
    part[t] += v;
    __syncthreads();
  }
  int run = part[t] - s;   // exclusive prefix
#pragma unroll
  for (int i = 0; i < 20; ++i) {
    int idx = t * 20 + i;
    if (idx < NA) off[idx] = run;
    run += loc[i];
  }
  if (t == 255) off[NA] = run;
}

__global__ __launch_bounds__(256) void sort_scatter_kernel(
    const int* __restrict__ dst, const int* __restrict__ off,
    int* __restrict__ cur, int* __restrict__ eidx, int* __restrict__ islot)
{
  int e = blockIdx.x * 256 + threadIdx.x;
  if (e >= NE) return;
  int d = dst[e];
  int pos = off[d] + atomicAdd(&cur[d], 1);
  eidx[pos] = e;
  islot[e] = pos;
}

__global__ __launch_bounds__(256) void ssort_kernel(
    const int* __restrict__ src, const int* __restrict__ islot,
    const int* __restrict__ soff, int* __restrict__ scur, int* __restrict__ sperm)
{
  int e = blockIdx.x * 256 + threadIdx.x;
  if (e >= NE) return;
  int s = src[e];
  int pos = soff[s] + atomicAdd(&scur[s], 1);
  sperm[pos] = islot[e];
}

// per sorted edge: rad[8], rh[3]
__global__ __launch_bounds__(256) void phi_kernel(
    const int* __restrict__ eidx, const float* __restrict__ r_ij, float* __restrict__ phi)
{
  int p = blockIdx.x * 256 + threadIdx.x;
  if (p >= NE) return;
  int e = eidx[p];
  const float rx = r_ij[e*3+0], ry = r_ij[e*3+1], rz = r_ij[e*3+2];
  const float r2 = rx*rx + ry*ry + rz*rz;
  const float r = sqrtf(r2 + 1e-12f);
#pragma unroll
  for (int k = 0; k < 8; ++k) {
    const float z = 7.f*r - (float)k;
    phi[(size_t)p*12 + k] = expf(-0.5f*z*z);
  }
  const float nn = sqrtf(49.f*r2 + 1e-12f);
  const float sc = (2.f / (1.f + expf(-nn)) - 1.f) / nn;
  phi[(size_t)p*12 + 8]  = 7.f*rx*sc;
  phi[(size_t)p*12 + 9]  = 7.f*ry*sc;
  phi[(size_t)p*12 + 10] = 7.f*rz*sc;
  phi[(size_t)p*12 + 11] = 0.f;
}

// ---------------------------------------------------------------------------
// Input projection (per atom)
// ---------------------------------------------------------------------------
__global__ __launch_bounds__(256) void proj_in_kernel(
    const float* __restrict__ x_a, const float* __restrict__ x_v, const float* __restrict__ x_d,
    const float* __restrict__ Wa, const float* __restrict__ Wv, const float* __restrict__ Wd,
    float* __restrict__ a_ws, float* __restrict__ v_ws, float* __restrict__ d_ws)
{
  __shared__ float xs[992];
  const int n = blockIdx.x, t = threadIdx.x;
  for (int q = t; q < 128; q += 256) xs[q]       = x_a[(size_t)n*128 + q];
  for (int q = t; q < 288; q += 256) xs[128 + q] = x_v[(size_t)n*288 + q];
  for (int q = t; q < 576; q += 256) xs[416 + q] = x_d[(size_t)n*576 + q];
  __syncthreads();
  {
    const float* W = &Wa[(size_t)t * 128];
    float acc = 0.f;
    for (int c = 0; c < 128; c += 4) acc += dot4f(*(const float4*)&W[c], *(const float4*)&xs[c]);
    int l = t >> 7, o = t & 127;
    a_ws[((size_t)l*NA + n)*128 + o] = acc;
  }
  if (t < 192) {
    const float* W = &Wv[(size_t)t * 96];
    float a0 = 0.f, a1 = 0.f, a2 = 0.f;
    for (int c = 0; c < 96; ++c) {
      float w = W[c]; const float* x = &xs[128 + c*3];
      a0 = fmaf(w, x[0], a0); a1 = fmaf(w, x[1], a1); a2 = fmaf(w, x[2], a2);
    }
    int l = t / 96, o = t % 96;
    float* dstp = &v_ws[(((size_t)l*NA + n)*96 + o)*3];
    dstp[0] = a0; dstp[1] = a1; dstp[2] = a2;
  }
  if (t < 128) {
    const float* W = &Wd[(size_t)t * 64];
    float acc[9] = {0,0,0,0,0,0,0,0,0};
    for (int c = 0; c < 64; ++c) {
      float w = W[c]; const float* x = &xs[416 + c*9];
#pragma unroll
      for (int j = 0; j < 9; ++j) acc[j] = fmaf(w, x[j], acc[j]);
    }
    int l = t >> 6, o = t & 63;
    float* dstp = &d_ws[(((size_t)l*NA + n)*64 + o)*9];
#pragma unroll
    for (int j = 0; j < 9; ++j) dstp[j] = acc[j];
  }
}

// ---------------------------------------------------------------------------
// Z helpers.  Pt layout [C][O][8].
// ---------------------------------------------------------------------------
template<int O, int C, int NMU>
__device__ __forceinline__ void zcompute(const float* __restrict__ Pt,
    const float* __restrict__ xl, int o, float z[8][NMU])
{
#pragma unroll
  for (int k = 0; k < 8; ++k)
#pragma unroll
    for (int m = 0; m < NMU; ++m) z[k][m] = 0.f;
  const float* p = Pt + o * 8;
#pragma unroll 2
  for (int c = 0; c < C; ++c, p += O*8) {
    const float4 pa = *(const float4*)p;
    const float4 pb = *(const float4*)(p + 4);
#pragma unroll
    for (int m = 0; m < NMU; ++m) {
      const float xv = xl[c * NMU + m];
      z[0][m] = fmaf(pa.x, xv, z[0][m]);
      z[1][m] = fmaf(pa.y, xv, z[1][m]);
      z[2][m] = fmaf(pa.z, xv, z[2][m]);
      z[3][m] = fmaf(pa.w, xv, z[3][m]);
      z[4][m] = fmaf(pb.x, xv, z[4][m]);
      z[5][m] = fmaf(pb.y, xv, z[5][m]);
      z[6][m] = fmaf(pb.z, xv, z[6][m]);
      z[7][m] = fmaf(pb.w, xv, z[7][m]);
    }
  }
}

// single-atom, NMU=9, half k range
template<int O, int C>
__device__ __forceinline__ void zcompute_k4(const float* __restrict__ Pt,
    const float* __restrict__ xl, int o, int kh, float z[4][9])
{
#pragma unroll
  for (int k = 0; k < 4; ++k)
#pragma unroll
    for (int m = 0; m < 9; ++m) z[k][m] = 0.f;
  const float* p = Pt + o * 8 + kh * 4;
#pragma unroll 2
  for (int c = 0; c < C; ++c, p += O*8) {
    const float4 pa = *(const float4*)p;
#pragma unroll
    for (int m = 0; m < 9; ++m) {
      const float xv = xl[c*9 + m];
      z[0][m] = fmaf(pa.x, xv, z[0][m]);
      z[1][m] = fmaf(pa.y, xv, z[1][m]);
      z[2][m] = fmaf(pa.z, xv, z[2][m]);
      z[3][m] = fmaf(pa.w, xv, z[3][m]);
    }
  }
}

// two atoms at once
template<int O, int C, int NMU>
__device__ __forceinline__ void zcompute2(const float* __restrict__ Pt,
    const float* __restrict__ x0, const float* __restrict__ x1,
    int o, float z[8][NMU][2])
{
#pragma unroll
  for (int k = 0; k < 8; ++k)
#pragma unroll
    for (int m = 0; m < NMU; ++m) { z[k][m][0] = 0.f; z[k][m][1] = 0.f; }
  const float* p = Pt + o * 8;
#pragma unroll 2
  for (int c = 0; c < C; ++c, p += O*8) {
    const float4 pa = *(const float4*)p;
    const float4 pb = *(const float4*)(p + 4);
#pragma unroll
    for (int m = 0; m < NMU; ++m) {
      const float a0 = x0[c*NMU + m], a1 = x1[c*NMU + m];
      z[0][m][0] = fmaf(pa.x, a0, z[0][m][0]); z[0][m][1] = fmaf(pa.x, a1, z[0][m][1]);
      z[1][m][0] = fmaf(pa.y, a0, z[1][m][0]); z[1][m][1] = fmaf(pa.y, a1, z[1][m][1]);
      z[2][m][0] = fmaf(pa.z, a0, z[2][m][0]); z[2][m][1] = fmaf(pa.z, a1, z[2][m][1]);
      z[3][m][0] = fmaf(pa.w, a0, z[3][m][0]); z[3][m][1] = fmaf(pa.w, a1, z[3][m][1]);
      z[4][m][0] = fmaf(pb.x, a0, z[4][m][0]); z[4][m][1] = fmaf(pb.x, a1, z[4][m][1]);
      z[5][m][0] = fmaf(pb.y, a0, z[5][m][0]); z[5][m][1] = fmaf(pb.y, a1, z[5][m][1]);
      z[6][m][0] = fmaf(pb.z, a0, z[6][m][0]); z[6][m][1] = fmaf(pb.z, a1, z[6][m][1]);
      z[7][m][0] = fmaf(pb.w, a0, z[7][m][0]); z[7][m][1] = fmaf(pb.w, a1, z[7][m][1]);
    }
  }
}

// two atoms, NMU=9, half k range
template<int O, int C>
__device__ __forceinline__ void zcompute2_k4(const float* __restrict__ Pt,
    const float* __restrict__ x0, const float* __restrict__ x1,
    int o, int kh, float z[4][9][2])
{
#pragma unroll
  for (int k = 0; k < 4; ++k)
#pragma unroll
    for (int m = 0; m < 9; ++m) { z[k][m][0] = 0.f; z[k][m][1] = 0.f; }
  const float* p = Pt + o * 8 + kh * 4;
#pragma unroll 2
  for (int c = 0; c < C; ++c, p += O*8) {
    const float4 pa = *(const float4*)p;
#pragma unroll
    for (int m = 0; m < 9; ++m) {
      const float a0 = x0[c*9 + m], a1 = x1[c*9 + m];
      z[0][m][0] = fmaf(pa.x, a0, z[0][m][0]); z[0][m][1] = fmaf(pa.x, a1, z[0][m][1]);
      z[1][m][0] = fmaf(pa.y, a0, z[1][m][0]); z[1][m][1] = fmaf(pa.y, a1, z[1][m][1]);
      z[2][m][0] = fmaf(pa.z, a0, z[2][m][0]); z[2][m][1] = fmaf(pa.z, a1, z[2][m][1]);
      z[3][m][0] = fmaf(pa.w, a0, z[3][m][0]); z[3][m][1] = fmaf(pa.w, a1, z[3][m][1]);
    }
  }
}

template<int NMU>
__device__ __forceinline__ float kdot(const float z[8][NMU], int m, const float* rr) {
  float s = z[0][m] * rr[0];
#pragma unroll
  for (int k = 1; k < 8; ++k) s = fmaf(z[k][m], rr[k], s);
  return s;
}
__device__ __forceinline__ float kdot_k4(const float z[4][9], int m, const float* rr) {
  float s = z[0][m] * rr[0];
#pragma unroll
  for (int k = 1; k < 4; ++k) s = fmaf(z[k][m], rr[k], s);
  return s;
}
template<int NMU>
__device__ __forceinline__ float kdot2(const float z[8][NMU][2], int m, int a, const float* rr) {
  float s = z[0][m][a] * rr[0];
#pragma unroll
  for (int k = 1; k < 8; ++k) s = fmaf(z[k][m][a], rr[k], s);
  return s;
}
__device__ __forceinline__ float kdot2_k4(const float z[4][9][2], int m, int a, const float* rr) {
  float s = z[0][m][a] * rr[0];
#pragma unroll
  for (int k = 1; k < 4; ++k) s = fmaf(z[k][m][a], rr[k], s);
  return s;
}

// shared feature layout (floats): XA [a][l][128]=512 | XV [a][l][288]=1152 | XD [a][l][576]=2304
#define F_XA 0
#define F_XV 512
#define F_XD 1664

template<int NT>
__device__ __forceinline__ void load_features(float* sm, int t, int n0, int n1,
    const float* __restrict__ a_ws, const float* __restrict__ v_ws, const float* __restrict__ d_ws)
{
  const int na[2] = {n0, n1};
  for (int q = t; q < 512; q += NT) {
    const int a = q >> 8, r = q & 255;
    sm[F_XA + q] = a_ws[((size_t)(r>>7)*NA + na[a])*128 + (r & 127)];
  }
  for (int q = t; q < 1152; q += NT) {
    const int a = q / 576, r = q % 576;
    sm[F_XV + q] = v_ws[((size_t)(r/288)*NA + na[a])*288 + (r % 288)];
  }
  for (int q = t; q < 2304; q += NT) {
    const int a = q / 1152, r = q % 1152;
    sm[F_XD + q] = d_ws[((size_t)(r/576)*NA + na[a])*576 + (r % 576)];
  }
}

// ---------------------------------------------------------------------------
// Pass A: psi_a (000,110,220). Block per atom pair, 256 thr, window 16.
// psi accumulated in LDS, thread-private slots ([slot][t], lane-stride 1).
// ---------------------------------------------------------------------------
__global__ __launch_bounds__(256, 2) void pass_a_kernel(
    const int* __restrict__ off, const float* __restrict__ phi,
    const float* __restrict__ Pt,
    const float* __restrict__ a_ws, const float* __restrict__ v_ws, const float* __restrict__ d_ws,
    unsigned short* __restrict__ psiA)
{
  __shared__ float sm[12544];
  const int t = threadIdx.x;
  const int n0 = blockIdx.x * 2, n1 = n0 + 1;
  const int off0 = off[n0], off1 = off[n1], off2 = off[n1 + 1];
  const int d0 = off1 - off0, d1 = off2 - off1;
  const int dm = d0 > d1 ? d0 : d1;
  if (dm == 0) return;
  const int o = t & 127, l = t >> 7;
  load_features<256>(sm, t, n0, n1, a_ws, v_ws, d_ws);
  const float* xa0 = &sm[F_XA + l*128];
  const float* xa1 = &sm[F_XA + 256 + l*128];
  const float* xv0 = &sm[F_XV + l*288];
  const float* xv1 = &sm[F_XV + 576 + l*288];
  const float* xd0 = &sm[F_XD + l*576];
  const float* xd1 = &sm[F_XD + 1152 + l*576];
  float* sphi = &sm[3968];   // 32 slots x 12
  float* psis = &sm[4352];   // [slot(32)][t(256)]

  const int nw = (dm + 15) >> 4;
  for (int w = 0; w < nw; ++w) {
    const int b0 = w * 16;
    __syncthreads();
    for (int q = t; q < 384; q += 256) {
      const int s = q / 12, f = q % 12, a = s >> 4, e = s & 15;
      const int d = a ? d1 : d0;
      const int gp = (a ? off1 : off0) + b0 + e;
      sphi[q] = (b0 + e < d) ? phi[(size_t)gp * 12 + f] : 0.f;
    }
    __syncthreads();

    { // 000 (initializes psi slots)
      float z[8][1][2];
      zcompute2<128,128,1>(Pt + OFF_000, xa0, xa1, o, z);
#pragma unroll
      for (int a = 0; a < 2; ++a)
#pragma unroll
        for (int e = 0; e < 16; ++e)
          psis[(a*16 + e)*256 + t] = kdot2<1>(z, 0, a, &sphi[(a*16 + e)*12]);
    }
    { // 110 (+=)
      float z[8][3][2];
      zcompute2<128,96,3>(Pt + OFF_110, xv0, xv1, o, z);
#pragma unroll
      for (int a = 0; a < 2; ++a)
#pragma unroll
        for (int e = 0; e < 16; ++e) {
          const float* ph = &sphi[(a*16 + e)*12];
          const float s0 = kdot2<3>(z,0,a,ph), s1 = kdot2<3>(z,1,a,ph), s2 = kdot2<3>(z,2,a,ph);
          psis[(a*16 + e)*256 + t] += ph[8]*s0 + ph[9]*s1 + ph[10]*s2;
        }
    }
#pragma unroll
    for (int kh = 0; kh < 2; ++kh) { // 220 k-split (+=)
      float z[4][9][2];
      zcompute2_k4<128,64>(Pt + OFF_220, xd0, xd1, o, kh, z);
#pragma unroll
      for (int a = 0; a < 2; ++a)
#pragma unroll
        for (int e = 0; e < 16; ++e) {
          const float* ph = &sphi[(a*16 + e)*12];
          const float* rr = ph + kh*4;
          float s[9];
#pragma unroll
          for (int m = 0; m < 9; ++m) s[m] = kdot2_k4(z, m, a, rr);
          const float q0 = ph[8], q1 = ph[9], q2 = ph[10];
          psis[(a*16 + e)*256 + t] += q0*(q0*s[0] + q1*s[1] + q2*s[2])
                                    + q1*(q0*s[3] + q1*s[4] + q2*s[5])
                                    + q2*(q0*s[6] + q1*s[7] + q2*s[8]);
        }
    }
#pragma unroll
    for (int e = 0; e < 16; ++e) {
      if (b0 + e < d0) psiA[(size_t)(off0 + b0 + e)*256 + t] = f2bf(psis[e*256 + t]);
      if (b0 + e < d1) psiA[(size_t)(off1 + b0 + e)*256 + t] = f2bf(psis[(16 + e)*256 + t]);
    }
  }
}

// ---------------------------------------------------------------------------
// Pass V: psi_v (011,101,121,211,111). Block per atom pair, 192 thr, window 8.
// psi in LDS [slot(16)][i(3)][t(192)].
// ---------------------------------------------------------------------------
__global__ __launch_bounds__(192, 2) void pass_v_kernel(
    const int* __restrict__ off, const float* __restrict__ phi,
    const float* __restrict__ Pt,
    const float* __restrict__ a_ws, const float* __restrict__ v_ws, const float* __restrict__ d_ws,
    unsigned short* __restrict__ psiV)
{
  __shared__ float sm[13376];
  const int t = threadIdx.x;
  const int n0 = blockIdx.x * 2, n1 = n0 + 1;
  const int off0 = off[n0], off1 = off[n1], off2 = off[n1 + 1];
  const int d0 = off1 - off0, d1 = off2 - off1;
  const int dm = d0 > d1 ? d0 : d1;
  if (dm == 0) return;
  const int o = t % 96, l = t / 96;
  load_features<192>(sm, t, n0, n1, a_ws, v_ws, d_ws);
  const float* xa0 = &sm[F_XA + l*128];
  const float* xa1 = &sm[F_XA + 256 + l*128];
  const float* xv0 = &sm[F_XV + l*288];
  const float* xv1 = &sm[F_XV + 576 + l*288];
  const float* xd0 = &sm[F_XD + l*576];
  const float* xd1 = &sm[F_XD + 1152 + l*576];
  float* sphi = &sm[3968];   // 16 slots x 12
  float* psis = &sm[4160];   // [slot(16)][i(3)][t(192)]

  const int nw = (dm + 7) >> 3;
  for (int w = 0; w < nw; ++w) {
    const int b0 = w * 8;
    __syncthreads();
    {
      const int q = t;  // 192 entries, one per thread
      const int s = q / 12, f = q % 12, a = s >> 3, e = s & 7;
      const int d = a ? d1 : d0;
      const int gp = (a ? off1 : off0) + b0 + e;
      sphi[q] = (b0 + e < d) ? phi[(size_t)gp * 12 + f] : 0.f;
    }
    __syncthreads();

    { // 011 (initializes)
      float z[8][3][2];
      zcompute2<96,96,3>(Pt + OFF_011, xv0, xv1, o, z);
#pragma unroll
      for (int a = 0; a < 2; ++a)
#pragma unroll
        for (int e = 0; e < 8; ++e) {
          const float* ph = &sphi[(a*8 + e)*12];
          float* pb = &psis[(a*8 + e)*576 + t];
          pb[0]   = kdot2<3>(z,0,a,ph);
          pb[192] = kdot2<3>(z,1,a,ph);
          pb[384] = kdot2<3>(z,2,a,ph);
        }
    }
    { // 101 (+=)
      float z[8][1][2];
      zcompute2<96,128,1>(Pt + OFF_101, xa0, xa1, o, z);
#pragma unroll
      for (int a = 0; a < 2; ++a)
#pragma unroll
        for (int e = 0; e < 8; ++e) {
          const float* ph = &sphi[(a*8 + e)*12];
          const float s0 = kdot2<1>(z,0,a,ph);
          float* pb = &psis[(a*8 + e)*576 + t];
          pb[0] += ph[8]*s0; pb[192] += ph[9]*s0; pb[384] += ph[10]*s0;
        }
    }
#pragma unroll
    for (int kh = 0; kh < 2; ++kh) { // 121 k-split (+=)
      float z[4][9][2];
      zcompute2_k4<96,64>(Pt + OFF_121, xd0, xd1, o, kh, z);
#pragma unroll
      for (int a = 0; a < 2; ++a)
#pragma unroll
        for (int e = 0; e < 8; ++e) {
          const float* ph = &sphi[(a*8 + e)*12];
          const float* rr = ph + kh*4;
          float s[9];
#pragma unroll
          for (int m = 0; m < 9; ++m) s[m] = kdot2_k4(z, m, a, rr);
          const float q0 = ph[8], q1 = ph[9], q2 = ph[10];
          float* pb = &psis[(a*8 + e)*576 + t];
          pb[0]   += q0*s[0] + q1*s[1] + q2*s[2];
          pb[192] += q0*s[3] + q1*s[4] + q2*s[5];
          pb[384] += q0*s[6] + q1*s[7] + q2*s[8];
        }
    }
    { // 211 (+=)
      float z[8][3][2];
      zcompute2<96,96,3>(Pt + OFF_211, xv0, xv1, o, z);
#pragma unroll
      for (int a = 0; a < 2; ++a)
#pragma unroll
        for (int e = 0; e < 8; ++e) {
          const float* ph = &sphi[(a*8 + e)*12];
          const float tt = ph[8]*kdot2<3>(z,0,a,ph) + ph[9]*kdot2<3>(z,1,a,ph) + ph[10]*kdot2<3>(z,2,a,ph);
          float* pb = &psis[(a*8 + e)*576 + t];
          pb[0] += ph[8]*tt; pb[192] += ph[9]*tt; pb[384] += ph[10]*tt;
        }
    }
    { // 111 (+=)
      float z[8][3][2];
      zcompute2<96,96,3>(Pt + OFF_111, xv0, xv1, o, z);
#pragma unroll
      for (int a = 0; a < 2; ++a)
#pragma unroll
        for (int e = 0; e < 8; ++e) {
          const float* ph = &sphi[(a*8 + e)*12];
          const float s0 = kdot2<3>(z,0,a,ph), s1 = kdot2<3>(z,1,a,ph), s2 = kdot2<3>(z,2,a,ph);
          const float q0 = ph[8], q1 = ph[9], q2 = ph[10];
          float* pb = &psis[(a*8 + e)*576 + t];
          pb[0]   += q1*s2 - q2*s1;
          pb[192] += q2*s0 - q0*s2;
          pb[384] += q0*s1 - q1*s0;
        }
    }
#pragma unroll
    for (int e = 0; e < 8; ++e) {
      if (b0 + e < d0) {
        const size_t b = (size_t)(off0 + b0 + e)*576 + l*288 + o*3;
        const float* pb = &psis[e*576 + t];
        psiV[b+0] = f2bf(pb[0]); psiV[b+1] = f2bf(pb[192]); psiV[b+2] = f2bf(pb[384]);
      }
      if (b0 + e < d1) {
        const size_t b = (size_t)(off1 + b0 + e)*576 + l*288 + o*3;
        const float* pb = &psis[(8 + e)*576 + t];
        psiV[b+0] = f2bf(pb[0]); psiV[b+1] = f2bf(pb[192]); psiV[b+2] = f2bf(pb[384]);
      }
    }
  }
}

// ---------------------------------------------------------------------------
// Pass D: psi_d (022,202,112,222,212). Block per atom pair, 256 thr:
// t = o(64) | l(2) | atom(2), window 6. psi in LDS [slot(12)][tl(128)][9].
// ---------------------------------------------------------------------------
__global__ __launch_bounds__(256, 2) void pass_d_kernel(
    const int* __restrict__ off, const float* __restrict__ phi,
    const float* __restrict__ Pt,
    const float* __restrict__ a_ws, const float* __restrict__ v_ws, const float* __restrict__ d_ws,
    unsigned short* __restrict__ psiD)
{
  __shared__ float sm[17936];
  const int t = threadIdx.x;
  const int n0 = blockIdx.x * 2, n1 = n0 + 1;
  const int off0 = off[n0], off1 = off[n1], off2 = off[n1 + 1];
  const int d0 = off1 - off0, d1 = off2 - off1;
  const int dm = d0 > d1 ? d0 : d1;
  if (dm == 0) return;
  const int o = t & 63, l = (t >> 6) & 1, a = t >> 7;
  const int tl = l*64 + o;
  load_features<256>(sm, t, n0, n1, a_ws, v_ws, d_ws);
  const float* xa = &sm[F_XA + a*256 + l*128];
  const float* xv = &sm[F_XV + a*576 + l*288];
  const float* xd = &sm[F_XD + a*1152 + l*576];
  float* sphi = &sm[3968];   // 12 slots x 12
  float* psis = &sm[4112];   // [slot(12)][tl(128)][9]
  const int offa = a ? off1 : off0;
  const int da   = a ? d1 : d0;

  const int nw = (dm + 5) / 6;
  for (int w = 0; w < nw; ++w) {
    const int b0 = w * 6;
    __syncthreads();
    for (int q = t; q < 144; q += 256) {
      const int s = q / 12, f = q % 12, a2 = s / 6, e = s % 6;
      const int d = a2 ? d1 : d0;
      const int gp = (a2 ? off1 : off0) + b0 + e;
      sphi[q] = (b0 + e < d) ? phi[(size_t)gp * 12 + f] : 0.f;
    }
    __syncthreads();

    { // 022 kh=0 (initializes)
      float z[4][9];
      zcompute_k4<64,64>(Pt + OFF_022, xd, o, 0, z);
#pragma unroll
      for (int e = 0; e < 6; ++e) {
        const float* rr = &sphi[(a*6 + e)*12];
        float* pb = &psis[((a*6 + e)*128 + tl)*9];
#pragma unroll
        for (int m = 0; m < 9; ++m) pb[m] = kdot_k4(z, m, rr);
      }
    }
    { // 022 kh=1 (+=)
      float z[4][9];
      zcompute_k4<64,64>(Pt + OFF_022, xd, o, 1, z);
#pragma unroll
      for (int e = 0; e < 6; ++e) {
        const float* rr = &sphi[(a*6 + e)*12] + 4;
        float* pb = &psis[((a*6 + e)*128 + tl)*9];
#pragma unroll
        for (int m = 0; m < 9; ++m) pb[m] += kdot_k4(z, m, rr);
      }
    }
    { // 202 (+=)
      float z[8][1];
      zcompute<64,128,1>(Pt + OFF_202, xa, o, z);
#pragma unroll
      for (int e = 0; e < 6; ++e) {
        const float* ph = &sphi[(a*6 + e)*12];
        const float s0 = kdot<1>(z, 0, ph);
        const float q0 = ph[8], q1 = ph[9], q2 = ph[10];
        float* pb = &psis[((a*6 + e)*128 + tl)*9];
        pb[0] += q0*q0*s0; pb[1] += q0*q1*s0; pb[2] += q0*q2*s0;
        pb[3] += q1*q0*s0; pb[4] += q1*q1*s0; pb[5] += q1*q2*s0;
        pb[6] += q2*q0*s0; pb[7] += q2*q1*s0; pb[8] += q2*q2*s0;
      }
    }
    { // 112 (+=)
      float z[8][3];
      zcompute<64,96,3>(Pt + OFF_112, xv, o, z);
#pragma unroll
      for (int e = 0; e < 6; ++e) {
        const float* ph = &sphi[(a*6 + e)*12];
        const float s0 = kdot<3>(z,0,ph), s1 = kdot<3>(z,1,ph), s2 = kdot<3>(z,2,ph);
        const float q0 = ph[8], q1 = ph[9], q2 = ph[10];
        float* pb = &psis[((a*6 + e)*128 + tl)*9];
        pb[0] += q0*s0; pb[1] += q0*s1; pb[2] += q0*s2;
        pb[3] += q1*s0; pb[4] += q1*s1; pb[5] += q1*s2;
        pb[6] += q2*s0; pb[7] += q2*s1; pb[8] += q2*s2;
      }
    }
#pragma unroll
    for (int kh = 0; kh < 2; ++kh) { // 222 k-split (+=)
      float z[4][9];
      zcompute_k4<64,64>(Pt + OFF_222, xd, o, kh, z);
#pragma unroll
      for (int e = 0; e < 6; ++e) {
        const float* ph = &sphi[(a*6 + e)*12];
        const float* rr = ph + kh*4;
        float s[9];
#pragma unroll
        for (int m = 0; m < 9; ++m) s[m] = kdot_k4(z, m, rr);
        const float q0 = ph[8], q1 = ph[9], q2 = ph[10];
        const float u0 = q0*s[0] + q1*s[3] + q2*s[6];
        const float u1 = q0*s[1] + q1*s[4] + q2*s[7];
        const float u2 = q0*s[2] + q1*s[5] + q2*s[8];
        float* pb = &psis[((a*6 + e)*128 + tl)*9];
        pb[0] += q0*u0; pb[1] += q0*u1; pb[2] += q0*u2;
        pb[3] += q1*u0; pb[4] += q1*u1; pb[5] += q1*u2;
        pb[6] += q2*u0; pb[7] += q2*u1; pb[8] += q2*u2;
      }
    }
    { // 212 (+=)
      float z[8][3];
      zcompute<64,96,3>(Pt + OFF_212, xv, o, z);
#pragma unroll
      for (int e = 0; e < 6; ++e) {
        const float* ph = &sphi[(a*6 + e)*12];
        const float s0 = kdot<3>(z,0,ph), s1 = kdot<3>(z,1,ph), s2 = kdot<3>(z,2,ph);
        const float q0 = ph[8], q1 = ph[9], q2 = ph[10];
        const float c0 = q1*s2 - q2*s1;
        const float c1 = q2*s0 - q0*s2;
        const float c2 = q0*s1 - q1*s0;
        float* pb = &psis[((a*6 + e)*128 + tl)*9];
        pb[0] += c0*q0; pb[1] += c0*q1; pb[2] += c0*q2;
        pb[3] += c1*q0; pb[4] += c1*q1; pb[5] += c1*q2;
        pb[6] += c2*q0; pb[7] += c2*q1; pb[8] += c2*q2;
      }
    }
#pragma unroll
    for (int e = 0; e < 6; ++e) {
      if (b0 + e < da) {
        const float* pb = &psis[((a*6 + e)*128 + tl)*9];
        unsigned short* bp = &psiD[(size_t)(offa + b0 + e)*1152 + tl*9];
#pragma unroll
        for (int j = 0; j < 9; ++j) bp[j] = f2bf(pb[j]);
      }
    }
  }
}

// ---------------------------------------------------------------------------
// Scalar MLP, 32 combos/block, in-place rewrite of psiA. 256 thr.
// ---------------------------------------------------------------------------
__global__ __launch_bounds__(256, 2) void mlp_a_kernel(
    unsigned short* __restrict__ psiA,
    const float* __restrict__ Wd_a,
    const float* __restrict__ W1, const float* __restrict__ b1,
    const float* __restrict__ W2, const float* __restrict__ b2,
    const float* __restrict__ W3, const float* __restrict__ b3)
{
  __shared__ float PA[32*128];   // 16 KB
  __shared__ float H1[32*256];   // 32 KB
  __shared__ float H2[32*256];   // 32 KB  -> exactly 80 KB
  const int t = threadIdx.x;
  const int cbase = blockIdx.x * 32;

  for (int q = t; q < 4096; q += 256)
    PA[q] = bf2f(psiA[(size_t)cbase*128 + q]);
  __syncthreads();
  { // h1 = lrelu(W1 x + b1): 64 pgroups(4 rows) x 4 jgroups(8 combos)
    const int p0 = (t & 63) * 4, j0 = (t >> 6) * 8;
    float acc[4][8];
#pragma unroll
    for (int r = 0; r < 4; ++r)
#pragma unroll
      for (int j = 0; j < 8; ++j) acc[r][j] = 0.f;
    for (int c = 0; c < 128; c += 4) {
      float4 w0 = *(const float4*)&W1[(size_t)(p0+0)*128 + c];
      float4 w1 = *(const float4*)&W1[(size_t)(p0+1)*128 + c];
      float4 w2 = *(const float4*)&W1[(size_t)(p0+2)*128 + c];
      float4 w3 = *(const float4*)&W1[(size_t)(p0+3)*128 + c];
#pragma unroll
      for (int j = 0; j < 8; ++j) {
        const float4 x = *(const float4*)&PA[(j0+j)*128 + c];
        acc[0][j] += dot4f(w0, x); acc[1][j] += dot4f(w1, x);
        acc[2][j] += dot4f(w2, x); acc[3][j] += dot4f(w3, x);
      }
    }
    const float bb0 = b1[p0], bb1 = b1[p0+1], bb2 = b1[p0+2], bb3 = b1[p0+3];
#pragma unroll
    for (int j = 0; j < 8; ++j) {
      float4 v; v.x = lrelu(acc[0][j]+bb0); v.y = lrelu(acc[1][j]+bb1);
      v.z = lrelu(acc[2][j]+bb2); v.w = lrelu(acc[3][j]+bb3);
      *(float4*)&H1[(j0+j)*256 + p0] = v;
    }
  }
  __syncthreads();
  { // h2 = lrelu(W2 h1 + b2)
    const int p0 = (t & 63) * 4, j0 = (t >> 6) * 8;
    float acc[4][8];
#pragma unroll
    for (int r = 0; r < 4; ++r)
#pragma unroll
      for (int j = 0; j < 8; ++j) acc[r][j] = 0.f;
    for (int c = 0; c < 256; c += 4) {
      float4 w0 = *(const float4*)&W2[(size_t)(p0+0)*256 + c];
      float4 w1 = *(const float4*)&W2[(size_t)(p0+1)*256 + c];
      float4 w2 = *(const float4*)&W2[(size_t)(p0+2)*256 + c];
      float4 w3 = *(const float4*)&W2[(size_t)(p0+3)*256 + c];
#pragma unroll
      for (int j = 0; j < 8; ++j) {
        const float4 x = *(const float4*)&H1[(j0+j)*256 + c];
        acc[0][j] += dot4f(w0, x); acc[1][j] += dot4f(w1, x);
        acc[2][j] += dot4f(w2, x); acc[3][j] += dot4f(w3, x);
      }
    }
    const float bb0 = b2[p0], bb1 = b2[p0+1], bb2 = b2[p0+2], bb3 = b2[p0+3];
#pragma unroll
    for (int j = 0; j < 8; ++j) {
      float4 v; v.x = lrelu(acc[0][j]+bb0); v.y = lrelu(acc[1][j]+bb1);
      v.z = lrelu(acc[2][j]+bb2); v.w = lrelu(acc[3][j]+bb3);
      *(float4*)&H2[(j0+j)*256 + p0] = v;
    }
  }
  __syncthreads();
  { // out = x + Wd x + W3 h2 + b3 -> psiA (bf16, in place)
    const int p0 = (t & 63) * 2, j0 = (t >> 6) * 8;
    float acc[2][8];
#pragma unroll
    for (int r = 0; r < 2; ++r)
#pragma unroll
      for (int j = 0; j < 8; ++j) acc[r][j] = 0.f;
    for (int c = 0; c < 128; c += 4) {
      float4 w0 = *(const float4*)&Wd_a[(size_t)(p0+0)*128 + c];
      float4 w1 = *(const float4*)&Wd_a[(size_t)(p0+1)*128 + c];
#pragma unroll
      for (int j = 0; j < 8; ++j) {
        const float4 x = *(const float4*)&PA[(j0+j)*128 + c];
        acc[0][j] += dot4f(w0, x); acc[1][j] += dot4f(w1, x);
      }
    }
    for (int c = 0; c < 256; c += 4) {
      float4 w0 = *(const float4*)&W3[(size_t)(p0+0)*256 + c];
      float4 w1 = *(const float4*)&W3[(size_t)(p0+1)*256 + c];
#pragma unroll
      for (int j = 0; j < 8; ++j) {
        const float4 x = *(const float4*)&H2[(j0+j)*256 + c];
        acc[0][j] += dot4f(w0, x); acc[1][j] += dot4f(w1, x);
      }
    }
    const float bb0 = b3[p0], bb1 = b3[p0+1];
#pragma unroll
    for (int j = 0; j < 8; ++j) {
      const float o0 = acc[0][j] + bb0 + PA[(j0+j)*128 + p0];
      const float o1 = acc[1][j] + bb1 + PA[(j0+j)*128 + p0 + 1];
      psiA[(size_t)(cbase + j0 + j)*128 + p0]     = f2bf(o0);
      psiA[(size_t)(cbase + j0 + j)*128 + p0 + 1] = f2bf(o1);
    }
  }
}

// ---------------------------------------------------------------------------
// Vector MLP, 8 combos/block, in-place rewrite of psiV. 192 thr.
// NEW mapping: lane p0 = t%24, combo j = t/24 (8 j-groups).
// Each thread owns rows p0+24r (r<8 for 192-wide, r<4 for 96-wide) of ONE
// combo -> LDS stores are lane-stride-1 (conflict-free), x-reads broadcast.
// ---------------------------------------------------------------------------
__global__ __launch_bounds__(192, 3) void mlp_v_kernel(
    unsigned short* __restrict__ psiV,
    const float* __restrict__ Vd, const float* __restrict__ V1,
    const float* __restrict__ V2, const float* __restrict__ V3)
{
  __shared__ float PV[8*288];    // [j][i][96]
  __shared__ float HV[8*576];    // [j][i][192]
  __shared__ float HV2[8*576];
  const int t = threadIdx.x;
  const int cbase = blockIdx.x * 8;
  const int p0 = t % 24, j = t / 24;

  for (int q = t; q < 2304; q += 192) {
    const int j2 = q / 288, r = q % 288, i = r / 96, o = r % 96;
    PV[q] = bf2f(psiV[(size_t)(cbase + j2)*288 + o*3 + i]);
  }
  __syncthreads();
  { // hv = tsig(V1 x): rows p0+24r, r=0..7
    float acc[8][3];
#pragma unroll
    for (int r = 0; r < 8; ++r) { acc[r][0]=0.f; acc[r][1]=0.f; acc[r][2]=0.f; }
#pragma unroll 2
    for (int c = 0; c < 96; c += 4) {
      float4 x0 = *(const float4*)&PV[j*288 + 0*96 + c];
      float4 x1 = *(const float4*)&PV[j*288 + 1*96 + c];
      float4 x2 = *(const float4*)&PV[j*288 + 2*96 + c];
#pragma unroll
      for (int r = 0; r < 8; ++r) {
        const float4 w = *(const float4*)&V1[(size_t)(p0 + 24*r)*96 + c];
        acc[r][0] += dot4f(w, x0); acc[r][1] += dot4f(w, x1); acc[r][2] += dot4f(w, x2);
      }
    }
#pragma unroll
    for (int r = 0; r < 8; ++r) {
      const float nn = sqrtf(acc[r][0]*acc[r][0] + acc[r][1]*acc[r][1] + acc[r][2]*acc[r][2] + 1e-12f);
      const float sc = (2.f / (1.f + expf(-nn)) - 1.f) / nn;
#pragma unroll
      for (int i = 0; i < 3; ++i) HV[j*576 + i*192 + p0 + 24*r] = acc[r][i]*sc;
    }
  }
  __syncthreads();
  { // hv2 = tsig(V2 hv): rows p0+24r, r=0..7
    float acc[8][3];
#pragma unroll
    for (int r = 0; r < 8; ++r) { acc[r][0]=0.f; acc[r][1]=0.f; acc[r][2]=0.f; }
#pragma unroll 2
    for (int c = 0; c < 192; c += 4) {
      float4 x0 = *(const float4*)&HV[j*576 + 0*192 + c];
      float4 x1 = *(const float4*)&HV[j*576 + 1*192 + c];
      float4 x2 = *(const float4*)&HV[j*576 + 2*192 + c];
#pragma unroll
      for (int r = 0; r < 8; ++r) {
        const float4 w = *(const float4*)&V2[(size_t)(p0 + 24*r)*192 + c];
        acc[r][0] += dot4f(w, x0); acc[r][1] += dot4f(w, x1); acc[r][2] += dot4f(w, x2);
      }
    }
#pragma unroll
    for (int r = 0; r < 8; ++r) {
      const float nn = sqrtf(acc[r][0]*acc[r][0] + acc[r][1]*acc[r][1] + acc[r][2]*acc[r][2] + 1e-12f);
      const float sc = (2.f / (1.f + expf(-nn)) - 1.f) / nn;
#pragma unroll
      for (int i = 0; i < 3; ++i) HV2[j*576 + i*192 + p0 + 24*r] = acc[r][i]*sc;
    }
  }
  __syncthreads();
  { // out = x + Vd x + V3 hv2 -> psiV: rows p0+24r, r=0..3
    float acc[4][3];
#pragma unroll
    for (int r = 0; r < 4; ++r) { acc[r][0]=0.f; acc[r][1]=0.f; acc[r][2]=0.f; }
#pragma unroll 2
    for (int c = 0; c < 96; c += 4) {
      float4 x0 = *(const float4*)&PV[j*288 + 0*96 + c];
      float4 x1 = *(const float4*)&PV[j*288 + 1*96 + c];
      float4 x2 = *(const float4*)&PV[j*288 + 2*96 + c];
#pragma unroll
      for (int r = 0; r < 4; ++r) {
        const float4 w = *(const float4*)&Vd[(size_t)(p0 + 24*r)*96 + c];
        acc[r][0] += dot4f(w, x0); acc[r][1] += dot4f(w, x1); acc[r][2] += dot4f(w, x2);
      }
    }
#pragma unroll 2
    for (int c = 0; c < 192; c += 4) {
      float4 x0 = *(const float4*)&HV2[j*576 + 0*192 + c];
      float4 x1 = *(const float4*)&HV2[j*576 + 1*192 + c];
      float4 x2 = *(const float4*)&HV2[j*576 + 2*192 + c];
#pragma unroll
      for (int r = 0; r < 4; ++r) {
        const float4 w = *(const float4*)&V3[(size_t)(p0 + 24*r)*192 + c];
        acc[r][0] += dot4f(w, x0); acc[r][1] += dot4f(w, x1); acc[r][2] += dot4f(w, x2);
      }
    }
#pragma unroll
    for (int r = 0; r < 4; ++r) {
      const int p = p0 + 24*r;
#pragma unroll
      for (int i = 0; i < 3; ++i) {
        const float v = acc[r][i] + PV[j*288 + i*96 + p];
        psiV[(size_t)(cbase + j)*288 + p*3 + i] = f2bf(v);
      }
    }
  }
}

// ---------------------------------------------------------------------------
// Gather (by src) + fused output projection. Block per src atom, 256 thr.
// ---------------------------------------------------------------------------
__global__ __launch_bounds__(256, 2) void gather_out_kernel(
    const int* __restrict__ soff, const int* __restrict__ sperm,
    const unsigned short* __restrict__ psiA, const unsigned short* __restrict__ psiV,
    const unsigned short* __restrict__ psiD,
    const float* __restrict__ Wa, const float* __restrict__ Wv, const float* __restrict__ Wd,
    float* __restrict__ out)
{
  __shared__ float bs[1984];
  const int n = blockIdx.x, t = threadIdx.x;
  const int s0 = soff[n], s1 = soff[n + 1];
  float acc[8];
#pragma unroll
  for (int u = 0; u < 8; ++u) acc[u] = 0.f;
  for (int p2 = s0; p2 < s1; ++p2) {
    const int slot = sperm[p2];
    const unsigned short* ra = psiA + (size_t)slot * 256;
    const unsigned short* rv = psiV + (size_t)slot * 576;
    const unsigned short* rd = psiD + (size_t)slot * 1152;
#pragma unroll
    for (int u = 0; u < 8; ++u) {
      const int v = t + 256 * u;
      if (v < 256)        acc[u] += bf2f(ra[v]);
      else if (v < 832)   acc[u] += bf2f(rv[v - 256]);
      else if (v < 1984)  acc[u] += bf2f(rd[v - 832]);
    }
  }
#pragma unroll
  for (int u = 0; u < 8; ++u) {
    const int v = t + 256 * u;
    if (v < 1984) bs[v] = acc[u];
  }
  __syncthreads();
  if (t < 128) {
    const float* W = &Wa[(size_t)t * 256];
    float a = 0.f;
    for (int c = 0; c < 256; c += 4) a += dot4f(*(const float4*)&W[c], *(const float4*)&bs[c]);
    out[(size_t)n*128 + t] = a;
  }
  if (t < 96) {
    const float* W = &Wv[(size_t)t * 192];
    float a0 = 0.f, a1 = 0.f, a2 = 0.f;
    for (int c = 0; c < 192; ++c) {
      const float w = W[c]; const float* x = &bs[256 + c*3];
      a0 = fmaf(w, x[0], a0); a1 = fmaf(w, x[1], a1); a2 = fmaf(w, x[2], a2);
    }
    float* d = &out[OUT_V + ((size_t)n*96 + t)*3];
    d[0] = a0; d[1] = a1; d[2] = a2;
  }
  if (t < 64) {
    const float* W = &Wd[(size_t)t * 128];
    float a[9] = {0,0,0,0,0,0,0,0,0};
    for (int c = 0; c < 128; ++c) {
      const float w = W[c]; const float* x = &bs[832 + c*9];
#pragma unroll
      for (int j = 0; j < 9; ++j) a[j] = fmaf(w, x[j], a[j]);
    }
    float* d = &out[OUT_D + ((size_t)n*64 + t)*9];
#pragma unroll
    for (int j = 0; j < 9; ++j) d[j] = a[j];
  }
}

// ---------------------------------------------------------------------------
// Host entry
// ---------------------------------------------------------------------------
extern "C" void kernel_launch(void* const* d_in, const int* in_sizes, int n_in,
                              void* d_out, int out_size, void* d_ws, size_t ws_size,
                              hipStream_t stream) {
  (void)in_sizes; (void)n_in; (void)out_size; (void)ws_size;
  const int*   src  = (const int*)d_in[0];
  const int*   dst  = (const int*)d_in[1];
  const float* r_ij = (const float*)d_in[2];
  const float* x_a  = (const float*)d_in[3];
  const float* x_v  = (const float*)d_in[4];
  const float* x_d  = (const float*)d_in[5];
  const float* P[13];
  for (int i = 0; i < 13; ++i) P[i] = (const float*)d_in[6 + i];
  const float* W_in_a  = (const float*)d_in[19];
  const float* W_in_v  = (const float*)d_in[20];
  const float* W_in_d  = (const float*)d_in[21];
  const float* W_out_a = (const float*)d_in[22];
  const float* W_out_v = (const float*)d_in[23];
  const float* W_out_d = (const float*)d_in[24];
  const float* Wd_a = (const float*)d_in[25];
  const float* W1   = (const float*)d_in[26];
  const float* b1   = (const float*)d_in[27];
  const float* W2   = (const float*)d_in[28];
  const float* b2   = (const float*)d_in[29];
  const float* W3   = (const float*)d_in[30];
  const float* b3   = (const float*)d_in[31];
  const float* Vd   = (const float*)d_in[32];
  const float* V1   = (const float*)d_in[33];
  const float* V2   = (const float*)d_in[34];
  const float* V3   = (const float*)d_in[35];

  float* ws = (float*)d_ws;
  float* Pt = ws;
  int*   ib = (int*)(ws + INT_OFF);
  unsigned short* psiA = (unsigned short*)(ws + PSIA_OFF);
  unsigned short* psiV = (unsigned short*)(ws + PSIV_OFF);
  unsigned short* psiD = (unsigned short*)(ws + PSID_OFF);

  // 1) transpose P tensors to [C][O][8]
  static const int Od[13] = {128,128,128, 96, 96, 96, 96, 96, 64, 64, 64, 64, 64};
  static const int Cd[13] = {128, 96, 64, 96,128, 64, 96, 96, 64,128, 96, 64, 96};
  for (int i = 0; i < 13; ++i) {
    const int total = Od[i] * Cd[i];
    transposeP_kernel<<<(total + 255) / 256, 256, 0, stream>>>(P[i], Pt + POFF[i], Od[i], Cd[i]);
  }

  // 2) zero sort counters
  hipMemsetAsync(ib, 0, 20000 * sizeof(int), stream);

  // 3) dst-sort + src-sort + per-edge encodings
  const int egrid = (NE + 255) / 256;
  hist_kernel<<<egrid, 256, 0, stream>>>(dst, ib + ICNT);
  scan_kernel<<<1, 256, 0, stream>>>(ib + ICNT, ib + IOFF);
  sort_scatter_kernel<<<egrid, 256, 0, stream>>>(dst, ib + IOFF, ib + ICUR, ib + IEIDX, ib + ISLOT);
  hist_kernel<<<egrid, 256, 0, stream>>>(src, ib + SCNT);
  scan_kernel<<<1, 256, 0, stream>>>(ib + SCNT, ib + SOFF);
  ssort_kernel<<<egrid, 256, 0, stream>>>(src, ib + ISLOT, ib + SOFF, ib + SCUR, ib + SPERM);
  phi_kernel<<<egrid, 256, 0, stream>>>(ib + IEIDX, r_ij, ws + PHI_OFF);

  // 4) input projections
  proj_in_kernel<<<NA, 256, 0, stream>>>(x_a, x_v, x_d, W_in_a, W_in_v, W_in_d,
                                         ws + A_OFF, ws + V_OFF, ws + D_OFF);

  // 5) messages: rank-specialized passes, block per atom pair, LDS psi
  pass_a_kernel<<<NA/2, 256, 0, stream>>>(ib + IOFF, ws + PHI_OFF, Pt,
                                          ws + A_OFF, ws + V_OFF, ws + D_OFF, psiA);
  pass_v_kernel<<<NA/2, 192, 0, stream>>>(ib + IOFF, ws + PHI_OFF, Pt,
                                          ws + A_OFF, ws + V_OFF, ws + D_OFF, psiV);
  pass_d_kernel<<<NA/2, 256, 0, stream>>>(ib + IOFF, ws + PHI_OFF, Pt,
                                          ws + A_OFF, ws + V_OFF, ws + D_OFF, psiD);

  // 6) edge MLPs (in place).  Combo counts are 2*NE for BOTH.
  mlp_a_kernel<<<(2*NE)/32, 256, 0, stream>>>(psiA, Wd_a, W1, b1, W2, b2, W3, b3);
  mlp_v_kernel<<<(2*NE)/8, 192, 0, stream>>>(psiV, Vd, V1, V2, V3);

  // 7) gather by src + fused output projection
  gather_out_kernel<<<NA, 256, 0, stream>>>(ib + SOFF, ib + SPERM,
                                            psiA, psiV, psiD,
                                            W_out_a, W_out_v, W_out_d, (float*)d_out);
}

// Round 8
// 4975.063 us; speedup vs baseline: 1.2743x; 1.2743x over previous
//
#include <hip/hip_runtime.h>
#include <hip/hip_bf16.h>

// ---------------------------------------------------------------------------
// Problem constants
// ---------------------------------------------------------------------------
#define NA 5000           // atoms
#define NE 40000          // edges
// DA=128, DV=96, DD=64, NL=8, L=2

// ---------------------------------------------------------------------------
// Workspace layout (float indices)
// ---------------------------------------------------------------------------
static const int POFF[13] = {0, 131072, 229376, 294912, 368640, 466944, 516096,
                             589824, 663552, 696320, 761856, 811008, 843776};
#define A_OFF    892928          // a  [2][NA][128] fp32
#define V_OFF    2172928         // v  [2][NA][288] fp32
#define D_OFF    5052928         // d  [2][NA][576] fp32
#define PHI_OFF  10812928        // [NE][12] fp32
#define PSIA_OFF 11292928        // bf16 [NE][256]  -> 5,120,000 floats
#define PSIV_OFF 16412928        // bf16 [NE][576]  -> 11,520,000 floats
#define PSID_OFF 27932928        // bf16 [NE][1152] -> 23,040,000 floats
#define INT_OFF  50972928
// int region (indices into (int*)(ws + INT_OFF))
#define ICNT  0        // [5000]
#define ICUR  5000     // [5000]
#define SCNT  10000    // [5000]
#define SCUR  15000    // [5000]
#define IOFF  20000    // [5001]
#define SOFF  25008    // [5001]
#define IEIDX 30016    // [NE]
#define ISLOT 70016    // [NE]
#define SPERM 110016   // [NE]

// output layout (floats)
#define OUT_V 640000
#define OUT_D 2080000

#define OFF_000 POFF[0]
#define OFF_110 POFF[1]
#define OFF_220 POFF[2]
#define OFF_011 POFF[3]
#define OFF_101 POFF[4]
#define OFF_121 POFF[5]
#define OFF_211 POFF[6]
#define OFF_111 POFF[7]
#define OFF_022 POFF[8]
#define OFF_202 POFF[9]
#define OFF_112 POFF[10]
#define OFF_222 POFF[11]
#define OFF_212 POFF[12]

__device__ __forceinline__ float dot4f(float4 a, float4 b) {
  return a.x*b.x + a.y*b.y + a.z*b.z + a.w*b.w;
}
__device__ __forceinline__ float lrelu(float x) { return x > 0.f ? x : 0.1f*x; }
__device__ __forceinline__ float bf2f(unsigned short u) {
  union { unsigned int i; float f; } x; x.i = ((unsigned int)u) << 16; return x.f;
}
__device__ __forceinline__ unsigned short f2bf(float f) {
  union { unsigned int i; float f; } x; x.f = f;
  unsigned int r = x.i + 0x7FFFu + ((x.i >> 16) & 1u);
  return (unsigned short)(r >> 16);
}

// ---------------------------------------------------------------------------
// P transpose: src [O][8][C] -> dst [C][O][8]
// ---------------------------------------------------------------------------
__global__ __launch_bounds__(256) void transposeP_kernel(
    const float* __restrict__ src, float* __restrict__ dst, int O, int C)
{
  int idx = blockIdx.x * 256 + threadIdx.x;
  if (idx >= O * C) return;
  int o = idx / C, c = idx % C;
#pragma unroll
  for (int k = 0; k < 8; ++k)
    dst[((size_t)c * O + o) * 8 + k] = src[((size_t)o * 8 + k) * C + c];
}

// ---------------------------------------------------------------------------
// Counting sorts
// ---------------------------------------------------------------------------
__global__ __launch_bounds__(256) void hist_kernel(const int* __restrict__ key, int* __restrict__ cnt) {
  int e = blockIdx.x * 256 + threadIdx.x;
  if (e < NE) atomicAdd(&cnt[key[e]], 1);
}

__global__ __launch_bounds__(256) void scan_kernel(const int* __restrict__ cnt, int* __restrict__ off) {
  __shared__ int part[256];
  const int t = threadIdx.x;
  int loc[20]; int s = 0;
#pragma unroll
  for (int i = 0; i < 20; ++i) {
    int idx = t * 20 + i;
    int v = (idx < NA) ? cnt[idx] : 0;
    loc[i] = v; s += v;
  }
  part[t] = s; __syncthreads();
  for (int ofs = 1; ofs < 256; ofs <<= 1) {
    int v = (t >= ofs) ? part[t - ofs] : 0;
    __syncthreads();
    part[t] += v;
    __syncthreads();
  }
  int run = part[t] - s;   // exclusive prefix
#pragma unroll
  for (int i = 0; i < 20; ++i) {
    int idx = t * 20 + i;
    if (idx < NA) off[idx] = run;
    run += loc[i];
  }
  if (t == 255) off[NA] = run;
}

__global__ __launch_bounds__(256) void sort_scatter_kernel(
    const int* __restrict__ dst, const int* __restrict__ off,
    int* __restrict__ cur, int* __restrict__ eidx, int* __restrict__ islot)
{
  int e = blockIdx.x * 256 + threadIdx.x;
  if (e >= NE) return;
  int d = dst[e];
  int pos = off[d] + atomicAdd(&cur[d], 1);
  eidx[pos] = e;
  islot[e] = pos;
}

__global__ __launch_bounds__(256) void ssort_kernel(
    const int* __restrict__ src, const int* __restrict__ islot,
    const int* __restrict__ soff, int* __restrict__ scur, int* __restrict__ sperm)
{
  int e = blockIdx.x * 256 + threadIdx.x;
  if (e >= NE) return;
  int s = src[e];
  int pos = soff[s] + atomicAdd(&scur[s], 1);
  sperm[pos] = islot[e];
}

// per sorted edge: rad[8], rh[3]
__global__ __launch_bounds__(256) void phi_kernel(
    const int* __restrict__ eidx, const float* __restrict__ r_ij, float* __restrict__ phi)
{
  int p = blockIdx.x * 256 + threadIdx.x;
  if (p >= NE) return;
  int e = eidx[p];
  const float rx = r_ij[e*3+0], ry = r_ij[e*3+1], rz = r_ij[e*3+2];
  const float r2 = rx*rx + ry*ry + rz*rz;
  const float r = sqrtf(r2 + 1e-12f);
#pragma unroll
  for (int k = 0; k < 8; ++k) {
    const float z = 7.f*r - (float)k;
    phi[(size_t)p*12 + k] = expf(-0.5f*z*z);
  }
  const float nn = sqrtf(49.f*r2 + 1e-12f);
  const float sc = (2.f / (1.f + expf(-nn)) - 1.f) / nn;
  phi[(size_t)p*12 + 8]  = 7.f*rx*sc;
  phi[(size_t)p*12 + 9]  = 7.f*ry*sc;
  phi[(size_t)p*12 + 10] = 7.f*rz*sc;
  phi[(size_t)p*12 + 11] = 0.f;
}

// ---------------------------------------------------------------------------
// Input projection (per atom)
// ---------------------------------------------------------------------------
__global__ __launch_bounds__(256) void proj_in_kernel(
    const float* __restrict__ x_a, const float* __restrict__ x_v, const float* __restrict__ x_d,
    const float* __restrict__ Wa, const float* __restrict__ Wv, const float* __restrict__ Wd,
    float* __restrict__ a_ws, float* __restrict__ v_ws, float* __restrict__ d_ws)
{
  __shared__ float xs[992];
  const int n = blockIdx.x, t = threadIdx.x;
  for (int q = t; q < 128; q += 256) xs[q]       = x_a[(size_t)n*128 + q];
  for (int q = t; q < 288; q += 256) xs[128 + q] = x_v[(size_t)n*288 + q];
  for (int q = t; q < 576; q += 256) xs[416 + q] = x_d[(size_t)n*576 + q];
  __syncthreads();
  {
    const float* W = &Wa[(size_t)t * 128];
    float acc = 0.f;
    for (int c = 0; c < 128; c += 4) acc += dot4f(*(const float4*)&W[c], *(const float4*)&xs[c]);
    int l = t >> 7, o = t & 127;
    a_ws[((size_t)l*NA + n)*128 + o] = acc;
  }
  if (t < 192) {
    const float* W = &Wv[(size_t)t * 96];
    float a0 = 0.f, a1 = 0.f, a2 = 0.f;
    for (int c = 0; c < 96; ++c) {
      float w = W[c]; const float* x = &xs[128 + c*3];
      a0 = fmaf(w, x[0], a0); a1 = fmaf(w, x[1], a1); a2 = fmaf(w, x[2], a2);
    }
    int l = t / 96, o = t % 96;
    float* dstp = &v_ws[(((size_t)l*NA + n)*96 + o)*3];
    dstp[0] = a0; dstp[1] = a1; dstp[2] = a2;
  }
  if (t < 128) {
    const float* W = &Wd[(size_t)t * 64];
    float acc[9] = {0,0,0,0,0,0,0,0,0};
    for (int c = 0; c < 64; ++c) {
      float w = W[c]; const float* x = &xs[416 + c*9];
#pragma unroll
      for (int j = 0; j < 9; ++j) acc[j] = fmaf(w, x[j], acc[j]);
    }
    int l = t >> 6, o = t & 63;
    float* dstp = &d_ws[(((size_t)l*NA + n)*64 + o)*9];
#pragma unroll
    for (int j = 0; j < 9; ++j) dstp[j] = acc[j];
  }
}

// ---------------------------------------------------------------------------
// Z helpers.  Pt layout [C][O][8].
// ---------------------------------------------------------------------------
template<int O, int C, int NMU>
__device__ __forceinline__ void zcompute(const float* __restrict__ Pt,
    const float* __restrict__ xl, int o, float z[8][NMU])
{
#pragma unroll
  for (int k = 0; k < 8; ++k)
#pragma unroll
    for (int m = 0; m < NMU; ++m) z[k][m] = 0.f;
  const float* p = Pt + o * 8;
#pragma unroll 2
  for (int c = 0; c < C; ++c, p += O*8) {
    const float4 pa = *(const float4*)p;
    const float4 pb = *(const float4*)(p + 4);
#pragma unroll
    for (int m = 0; m < NMU; ++m) {
      const float xv = xl[c * NMU + m];
      z[0][m] = fmaf(pa.x, xv, z[0][m]);
      z[1][m] = fmaf(pa.y, xv, z[1][m]);
      z[2][m] = fmaf(pa.z, xv, z[2][m]);
      z[3][m] = fmaf(pa.w, xv, z[3][m]);
      z[4][m] = fmaf(pb.x, xv, z[4][m]);
      z[5][m] = fmaf(pb.y, xv, z[5][m]);
      z[6][m] = fmaf(pb.z, xv, z[6][m]);
      z[7][m] = fmaf(pb.w, xv, z[7][m]);
    }
  }
}

// single-atom, NMU=9, half k range
template<int O, int C>
__device__ __forceinline__ void zcompute_k4(const float* __restrict__ Pt,
    const float* __restrict__ xl, int o, int kh, float z[4][9])
{
#pragma unroll
  for (int k = 0; k < 4; ++k)
#pragma unroll
    for (int m = 0; m < 9; ++m) z[k][m] = 0.f;
  const float* p = Pt + o * 8 + kh * 4;
#pragma unroll 2
  for (int c = 0; c < C; ++c, p += O*8) {
    const float4 pa = *(const float4*)p;
#pragma unroll
    for (int m = 0; m < 9; ++m) {
      const float xv = xl[c*9 + m];
      z[0][m] = fmaf(pa.x, xv, z[0][m]);
      z[1][m] = fmaf(pa.y, xv, z[1][m]);
      z[2][m] = fmaf(pa.z, xv, z[2][m]);
      z[3][m] = fmaf(pa.w, xv, z[3][m]);
    }
  }
}

// two atoms at once
template<int O, int C, int NMU>
__device__ __forceinline__ void zcompute2(const float* __restrict__ Pt,
    const float* __restrict__ x0, const float* __restrict__ x1,
    int o, float z[8][NMU][2])
{
#pragma unroll
  for (int k = 0; k < 8; ++k)
#pragma unroll
    for (int m = 0; m < NMU; ++m) { z[k][m][0] = 0.f; z[k][m][1] = 0.f; }
  const float* p = Pt + o * 8;
#pragma unroll 2
  for (int c = 0; c < C; ++c, p += O*8) {
    const float4 pa = *(const float4*)p;
    const float4 pb = *(const float4*)(p + 4);
#pragma unroll
    for (int m = 0; m < NMU; ++m) {
      const float a0 = x0[c*NMU + m], a1 = x1[c*NMU + m];
      z[0][m][0] = fmaf(pa.x, a0, z[0][m][0]); z[0][m][1] = fmaf(pa.x, a1, z[0][m][1]);
      z[1][m][0] = fmaf(pa.y, a0, z[1][m][0]); z[1][m][1] = fmaf(pa.y, a1, z[1][m][1]);
      z[2][m][0] = fmaf(pa.z, a0, z[2][m][0]); z[2][m][1] = fmaf(pa.z, a1, z[2][m][1]);
      z[3][m][0] = fmaf(pa.w, a0, z[3][m][0]); z[3][m][1] = fmaf(pa.w, a1, z[3][m][1]);
      z[4][m][0] = fmaf(pb.x, a0, z[4][m][0]); z[4][m][1] = fmaf(pb.x, a1, z[4][m][1]);
      z[5][m][0] = fmaf(pb.y, a0, z[5][m][0]); z[5][m][1] = fmaf(pb.y, a1, z[5][m][1]);
      z[6][m][0] = fmaf(pb.z, a0, z[6][m][0]); z[6][m][1] = fmaf(pb.z, a1, z[6][m][1]);
      z[7][m][0] = fmaf(pb.w, a0, z[7][m][0]); z[7][m][1] = fmaf(pb.w, a1, z[7][m][1]);
    }
  }
}

// two atoms, NMU=9, half k range
template<int O, int C>
__device__ __forceinline__ void zcompute2_k4(const float* __restrict__ Pt,
    const float* __restrict__ x0, const float* __restrict__ x1,
    int o, int kh, float z[4][9][2])
{
#pragma unroll
  for (int k = 0; k < 4; ++k)
#pragma unroll
    for (int m = 0; m < 9; ++m) { z[k][m][0] = 0.f; z[k][m][1] = 0.f; }
  const float* p = Pt + o * 8 + kh * 4;
#pragma unroll 2
  for (int c = 0; c < C; ++c, p += O*8) {
    const float4 pa = *(const float4*)p;
#pragma unroll
    for (int m = 0; m < 9; ++m) {
      const float a0 = x0[c*9 + m], a1 = x1[c*9 + m];
      z[0][m][0] = fmaf(pa.x, a0, z[0][m][0]); z[0][m][1] = fmaf(pa.x, a1, z[0][m][1]);
      z[1][m][0] = fmaf(pa.y, a0, z[1][m][0]); z[1][m][1] = fmaf(pa.y, a1, z[1][m][1]);
      z[2][m][0] = fmaf(pa.z, a0, z[2][m][0]); z[2][m][1] = fmaf(pa.z, a1, z[2][m][1]);
      z[3][m][0] = fmaf(pa.w, a0, z[3][m][0]); z[3][m][1] = fmaf(pa.w, a1, z[3][m][1]);
    }
  }
}

template<int NMU>
__device__ __forceinline__ float kdot(const float z[8][NMU], int m, const float* rr) {
  float s = z[0][m] * rr[0];
#pragma unroll
  for (int k = 1; k < 8; ++k) s = fmaf(z[k][m], rr[k], s);
  return s;
}
__device__ __forceinline__ float kdot_k4(const float z[4][9], int m, const float* rr) {
  float s = z[0][m] * rr[0];
#pragma unroll
  for (int k = 1; k < 4; ++k) s = fmaf(z[k][m], rr[k], s);
  return s;
}
template<int NMU>
__device__ __forceinline__ float kdot2(const float z[8][NMU][2], int m, int a, const float* rr) {
  float s = z[0][m][a] * rr[0];
#pragma unroll
  for (int k = 1; k < 8; ++k) s = fmaf(z[k][m][a], rr[k], s);
  return s;
}
__device__ __forceinline__ float kdot2_k4(const float z[4][9][2], int m, int a, const float* rr) {
  float s = z[0][m][a] * rr[0];
#pragma unroll
  for (int k = 1; k < 4; ++k) s = fmaf(z[k][m][a], rr[k], s);
  return s;
}

// shared feature layout (floats): XA [a][l][128]=512 | XV [a][l][288]=1152 | XD [a][l][576]=2304
#define F_XA 0
#define F_XV 512
#define F_XD 1664

template<int NT>
__device__ __forceinline__ void load_features(float* sm, int t, int n0, int n1,
    const float* __restrict__ a_ws, const float* __restrict__ v_ws, const float* __restrict__ d_ws)
{
  const int na[2] = {n0, n1};
  for (int q = t; q < 512; q += NT) {
    const int a = q >> 8, r = q & 255;
    sm[F_XA + q] = a_ws[((size_t)(r>>7)*NA + na[a])*128 + (r & 127)];
  }
  for (int q = t; q < 1152; q += NT) {
    const int a = q / 576, r = q % 576;
    sm[F_XV + q] = v_ws[((size_t)(r/288)*NA + na[a])*288 + (r % 288)];
  }
  for (int q = t; q < 2304; q += NT) {
    const int a = q / 1152, r = q % 1152;
    sm[F_XD + q] = d_ws[((size_t)(r/576)*NA + na[a])*576 + (r % 576)];
  }
}

// ---------------------------------------------------------------------------
// Pass A: psi_a (000,110,220). Block per atom pair, 256 thr, window 16.
// psi accumulated in LDS, thread-private slots ([slot][t], lane-stride 1).
// ---------------------------------------------------------------------------
__global__ __launch_bounds__(256, 2) void pass_a_kernel(
    const int* __restrict__ off, const float* __restrict__ phi,
    const float* __restrict__ Pt,
    const float* __restrict__ a_ws, const float* __restrict__ v_ws, const float* __restrict__ d_ws,
    unsigned short* __restrict__ psiA)
{
  __shared__ float sm[12544];
  const int t = threadIdx.x;
  const int n0 = blockIdx.x * 2, n1 = n0 + 1;
  const int off0 = off[n0], off1 = off[n1], off2 = off[n1 + 1];
  const int d0 = off1 - off0, d1 = off2 - off1;
  const int dm = d0 > d1 ? d0 : d1;
  if (dm == 0) return;
  const int o = t & 127, l = t >> 7;
  load_features<256>(sm, t, n0, n1, a_ws, v_ws, d_ws);
  const float* xa0 = &sm[F_XA + l*128];
  const float* xa1 = &sm[F_XA + 256 + l*128];
  const float* xv0 = &sm[F_XV + l*288];
  const float* xv1 = &sm[F_XV + 576 + l*288];
  const float* xd0 = &sm[F_XD + l*576];
  const float* xd1 = &sm[F_XD + 1152 + l*576];
  float* sphi = &sm[3968];   // 32 slots x 12
  float* psis = &sm[4352];   // [slot(32)][t(256)]

  const int nw = (dm + 15) >> 4;
  for (int w = 0; w < nw; ++w) {
    const int b0 = w * 16;
    __syncthreads();
    for (int q = t; q < 384; q += 256) {
      const int s = q / 12, f = q % 12, a = s >> 4, e = s & 15;
      const int d = a ? d1 : d0;
      const int gp = (a ? off1 : off0) + b0 + e;
      sphi[q] = (b0 + e < d) ? phi[(size_t)gp * 12 + f] : 0.f;
    }
    __syncthreads();

    { // 000 (initializes psi slots)
      float z[8][1][2];
      zcompute2<128,128,1>(Pt + OFF_000, xa0, xa1, o, z);
#pragma unroll
      for (int a = 0; a < 2; ++a)
#pragma unroll
        for (int e = 0; e < 16; ++e)
          psis[(a*16 + e)*256 + t] = kdot2<1>(z, 0, a, &sphi[(a*16 + e)*12]);
    }
    { // 110 (+=)
      float z[8][3][2];
      zcompute2<128,96,3>(Pt + OFF_110, xv0, xv1, o, z);
#pragma unroll
      for (int a = 0; a < 2; ++a)
#pragma unroll
        for (int e = 0; e < 16; ++e) {
          const float* ph = &sphi[(a*16 + e)*12];
          const float s0 = kdot2<3>(z,0,a,ph), s1 = kdot2<3>(z,1,a,ph), s2 = kdot2<3>(z,2,a,ph);
          psis[(a*16 + e)*256 + t] += ph[8]*s0 + ph[9]*s1 + ph[10]*s2;
        }
    }
#pragma unroll
    for (int kh = 0; kh < 2; ++kh) { // 220 k-split (+=)
      float z[4][9][2];
      zcompute2_k4<128,64>(Pt + OFF_220, xd0, xd1, o, kh, z);
#pragma unroll
      for (int a = 0; a < 2; ++a)
#pragma unroll
        for (int e = 0; e < 16; ++e) {
          const float* ph = &sphi[(a*16 + e)*12];
          const float* rr = ph + kh*4;
          float s[9];
#pragma unroll
          for (int m = 0; m < 9; ++m) s[m] = kdot2_k4(z, m, a, rr);
          const float q0 = ph[8], q1 = ph[9], q2 = ph[10];
          psis[(a*16 + e)*256 + t] += q0*(q0*s[0] + q1*s[1] + q2*s[2])
                                    + q1*(q0*s[3] + q1*s[4] + q2*s[5])
                                    + q2*(q0*s[6] + q1*s[7] + q2*s[8]);
        }
    }
#pragma unroll
    for (int e = 0; e < 16; ++e) {
      if (b0 + e < d0) psiA[(size_t)(off0 + b0 + e)*256 + t] = f2bf(psis[e*256 + t]);
      if (b0 + e < d1) psiA[(size_t)(off1 + b0 + e)*256 + t] = f2bf(psis[(16 + e)*256 + t]);
    }
  }
}

// ---------------------------------------------------------------------------
// Pass V: psi_v (011,101,121,211,111). Block per atom pair, 192 thr, window 8.
// psi in LDS [slot(16)][i(3)][t(192)].
// ---------------------------------------------------------------------------
__global__ __launch_bounds__(192, 2) void pass_v_kernel(
    const int* __restrict__ off, const float* __restrict__ phi,
    const float* __restrict__ Pt,
    const float* __restrict__ a_ws, const float* __restrict__ v_ws, const float* __restrict__ d_ws,
    unsigned short* __restrict__ psiV)
{
  __shared__ float sm[13376];
  const int t = threadIdx.x;
  const int n0 = blockIdx.x * 2, n1 = n0 + 1;
  const int off0 = off[n0], off1 = off[n1], off2 = off[n1 + 1];
  const int d0 = off1 - off0, d1 = off2 - off1;
  const int dm = d0 > d1 ? d0 : d1;
  if (dm == 0) return;
  const int o = t % 96, l = t / 96;
  load_features<192>(sm, t, n0, n1, a_ws, v_ws, d_ws);
  const float* xa0 = &sm[F_XA + l*128];
  const float* xa1 = &sm[F_XA + 256 + l*128];
  const float* xv0 = &sm[F_XV + l*288];
  const float* xv1 = &sm[F_XV + 576 + l*288];
  const float* xd0 = &sm[F_XD + l*576];
  const float* xd1 = &sm[F_XD + 1152 + l*576];
  float* sphi = &sm[3968];   // 16 slots x 12
  float* psis = &sm[4160];   // [slot(16)][i(3)][t(192)]

  const int nw = (dm + 7) >> 3;
  for (int w = 0; w < nw; ++w) {
    const int b0 = w * 8;
    __syncthreads();
    {
      const int q = t;  // 192 entries, one per thread
      const int s = q / 12, f = q % 12, a = s >> 3, e = s & 7;
      const int d = a ? d1 : d0;
      const int gp = (a ? off1 : off0) + b0 + e;
      sphi[q] = (b0 + e < d) ? phi[(size_t)gp * 12 + f] : 0.f;
    }
    __syncthreads();

    { // 011 (initializes)
      float z[8][3][2];
      zcompute2<96,96,3>(Pt + OFF_011, xv0, xv1, o, z);
#pragma unroll
      for (int a = 0; a < 2; ++a)
#pragma unroll
        for (int e = 0; e < 8; ++e) {
          const float* ph = &sphi[(a*8 + e)*12];
          float* pb = &psis[(a*8 + e)*576 + t];
          pb[0]   = kdot2<3>(z,0,a,ph);
          pb[192] = kdot2<3>(z,1,a,ph);
          pb[384] = kdot2<3>(z,2,a,ph);
        }
    }
    { // 101 (+=)
      float z[8][1][2];
      zcompute2<96,128,1>(Pt + OFF_101, xa0, xa1, o, z);
#pragma unroll
      for (int a = 0; a < 2; ++a)
#pragma unroll
        for (int e = 0; e < 8; ++e) {
          const float* ph = &sphi[(a*8 + e)*12];
          const float s0 = kdot2<1>(z,0,a,ph);
          float* pb = &psis[(a*8 + e)*576 + t];
          pb[0] += ph[8]*s0; pb[192] += ph[9]*s0; pb[384] += ph[10]*s0;
        }
    }
#pragma unroll
    for (int kh = 0; kh < 2; ++kh) { // 121 k-split (+=)
      float z[4][9][2];
      zcompute2_k4<96,64>(Pt + OFF_121, xd0, xd1, o, kh, z);
#pragma unroll
      for (int a = 0; a < 2; ++a)
#pragma unroll
        for (int e = 0; e < 8; ++e) {
          const float* ph = &sphi[(a*8 + e)*12];
          const float* rr = ph + kh*4;
          float s[9];
#pragma unroll
          for (int m = 0; m < 9; ++m) s[m] = kdot2_k4(z, m, a, rr);
          const float q0 = ph[8], q1 = ph[9], q2 = ph[10];
          float* pb = &psis[(a*8 + e)*576 + t];
          pb[0]   += q0*s[0] + q1*s[1] + q2*s[2];
          pb[192] += q0*s[3] + q1*s[4] + q2*s[5];
          pb[384] += q0*s[6] + q1*s[7] + q2*s[8];
        }
    }
    { // 211 (+=)
      float z[8][3][2];
      zcompute2<96,96,3>(Pt + OFF_211, xv0, xv1, o, z);
#pragma unroll
      for (int a = 0; a < 2; ++a)
#pragma unroll
        for (int e = 0; e < 8; ++e) {
          const float* ph = &sphi[(a*8 + e)*12];
          const float tt = ph[8]*kdot2<3>(z,0,a,ph) + ph[9]*kdot2<3>(z,1,a,ph) + ph[10]*kdot2<3>(z,2,a,ph);
          float* pb = &psis[(a*8 + e)*576 + t];
          pb[0] += ph[8]*tt; pb[192] += ph[9]*tt; pb[384] += ph[10]*tt;
        }
    }
    { // 111 (+=)
      float z[8][3][2];
      zcompute2<96,96,3>(Pt + OFF_111, xv0, xv1, o, z);
#pragma unroll
      for (int a = 0; a < 2; ++a)
#pragma unroll
        for (int e = 0; e < 8; ++e) {
          const float* ph = &sphi[(a*8 + e)*12];
          const float s0 = kdot2<3>(z,0,a,ph), s1 = kdot2<3>(z,1,a,ph), s2 = kdot2<3>(z,2,a,ph);
          const float q0 = ph[8], q1 = ph[9], q2 = ph[10];
          float* pb = &psis[(a*8 + e)*576 + t];
          pb[0]   += q1*s2 - q2*s1;
          pb[192] += q2*s0 - q0*s2;
          pb[384] += q0*s1 - q1*s0;
        }
    }
#pragma unroll
    for (int e = 0; e < 8; ++e) {
      if (b0 + e < d0) {
        const size_t b = (size_t)(off0 + b0 + e)*576 + l*288 + o*3;
        const float* pb = &psis[e*576 + t];
        psiV[b+0] = f2bf(pb[0]); psiV[b+1] = f2bf(pb[192]); psiV[b+2] = f2bf(pb[384]);
      }
      if (b0 + e < d1) {
        const size_t b = (size_t)(off1 + b0 + e)*576 + l*288 + o*3;
        const float* pb = &psis[(8 + e)*576 + t];
        psiV[b+0] = f2bf(pb[0]); psiV[b+1] = f2bf(pb[192]); psiV[b+2] = f2bf(pb[384]);
      }
    }
  }
}

// ---------------------------------------------------------------------------
// Pass D: psi_d (022,202,112,222,212). Block per atom pair, 256 thr:
// t = o(64) | l(2) | atom(2), window 6. psi in LDS [slot(12)][tl(128)][9].
// ---------------------------------------------------------------------------
__global__ __launch_bounds__(256, 2) void pass_d_kernel(
    const int* __restrict__ off, const float* __restrict__ phi,
    const float* __restrict__ Pt,
    const float* __restrict__ a_ws, const float* __restrict__ v_ws, const float* __restrict__ d_ws,
    unsigned short* __restrict__ psiD)
{
  __shared__ float sm[17936];
  const int t = threadIdx.x;
  const int n0 = blockIdx.x * 2, n1 = n0 + 1;
  const int off0 = off[n0], off1 = off[n1], off2 = off[n1 + 1];
  const int d0 = off1 - off0, d1 = off2 - off1;
  const int dm = d0 > d1 ? d0 : d1;
  if (dm == 0) return;
  const int o = t & 63, l = (t >> 6) & 1, a = t >> 7;
  const int tl = l*64 + o;
  load_features<256>(sm, t, n0, n1, a_ws, v_ws, d_ws);
  const float* xa = &sm[F_XA + a*256 + l*128];
  const float* xv = &sm[F_XV + a*576 + l*288];
  const float* xd = &sm[F_XD + a*1152 + l*576];
  float* sphi = &sm[3968];   // 12 slots x 12
  float* psis = &sm[4112];   // [slot(12)][tl(128)][9]
  const int offa = a ? off1 : off0;
  const int da   = a ? d1 : d0;

  const int nw = (dm + 5) / 6;
  for (int w = 0; w < nw; ++w) {
    const int b0 = w * 6;
    __syncthreads();
    for (int q = t; q < 144; q += 256) {
      const int s = q / 12, f = q % 12, a2 = s / 6, e = s % 6;
      const int d = a2 ? d1 : d0;
      const int gp = (a2 ? off1 : off0) + b0 + e;
      sphi[q] = (b0 + e < d) ? phi[(size_t)gp * 12 + f] : 0.f;
    }
    __syncthreads();

    { // 022 kh=0 (initializes)
      float z[4][9];
      zcompute_k4<64,64>(Pt + OFF_022, xd, o, 0, z);
#pragma unroll
      for (int e = 0; e < 6; ++e) {
        const float* rr = &sphi[(a*6 + e)*12];
        float* pb = &psis[((a*6 + e)*128 + tl)*9];
#pragma unroll
        for (int m = 0; m < 9; ++m) pb[m] = kdot_k4(z, m, rr);
      }
    }
    { // 022 kh=1 (+=)
      float z[4][9];
      zcompute_k4<64,64>(Pt + OFF_022, xd, o, 1, z);
#pragma unroll
      for (int e = 0; e < 6; ++e) {
        const float* rr = &sphi[(a*6 + e)*12] + 4;
        float* pb = &psis[((a*6 + e)*128 + tl)*9];
#pragma unroll
        for (int m = 0; m < 9; ++m) pb[m] += kdot_k4(z, m, rr);
      }
    }
    { // 202 (+=)
      float z[8][1];
      zcompute<64,128,1>(Pt + OFF_202, xa, o, z);
#pragma unroll
      for (int e = 0; e < 6; ++e) {
        const float* ph = &sphi[(a*6 + e)*12];
        const float s0 = kdot<1>(z, 0, ph);
        const float q0 = ph[8], q1 = ph[9], q2 = ph[10];
        float* pb = &psis[((a*6 + e)*128 + tl)*9];
        pb[0] += q0*q0*s0; pb[1] += q0*q1*s0; pb[2] += q0*q2*s0;
        pb[3] += q1*q0*s0; pb[4] += q1*q1*s0; pb[5] += q1*q2*s0;
        pb[6] += q2*q0*s0; pb[7] += q2*q1*s0; pb[8] += q2*q2*s0;
      }
    }
    { // 112 (+=)
      float z[8][3];
      zcompute<64,96,3>(Pt + OFF_112, xv, o, z);
#pragma unroll
      for (int e = 0; e < 6; ++e) {
        const float* ph = &sphi[(a*6 + e)*12];
        const float s0 = kdot<3>(z,0,ph), s1 = kdot<3>(z,1,ph), s2 = kdot<3>(z,2,ph);
        const float q0 = ph[8], q1 = ph[9], q2 = ph[10];
        float* pb = &psis[((a*6 + e)*128 + tl)*9];
        pb[0] += q0*s0; pb[1] += q0*s1; pb[2] += q0*s2;
        pb[3] += q1*s0; pb[4] += q1*s1; pb[5] += q1*s2;
        pb[6] += q2*s0; pb[7] += q2*s1; pb[8] += q2*s2;
      }
    }
#pragma unroll
    for (int kh = 0; kh < 2; ++kh) { // 222 k-split (+=)
      float z[4][9];
      zcompute_k4<64,64>(Pt + OFF_222, xd, o, kh, z);
#pragma unroll
      for (int e = 0; e < 6; ++e) {
        const float* ph = &sphi[(a*6 + e)*12];
        const float* rr = ph + kh*4;
        float s[9];
#pragma unroll
        for (int m = 0; m < 9; ++m) s[m] = kdot_k4(z, m, rr);
        const float q0 = ph[8], q1 = ph[9], q2 = ph[10];
        const float u0 = q0*s[0] + q1*s[3] + q2*s[6];
        const float u1 = q0*s[1] + q1*s[4] + q2*s[7];
        const float u2 = q0*s[2] + q1*s[5] + q2*s[8];
        float* pb = &psis[((a*6 + e)*128 + tl)*9];
        pb[0] += q0*u0; pb[1] += q0*u1; pb[2] += q0*u2;
        pb[3] += q1*u0; pb[4] += q1*u1; pb[5] += q1*u2;
        pb[6] += q2*u0; pb[7] += q2*u1; pb[8] += q2*u2;
      }
    }
    { // 212 (+=)
      float z[8][3];
      zcompute<64,96,3>(Pt + OFF_212, xv, o, z);
#pragma unroll
      for (int e = 0; e < 6; ++e) {
        const float* ph = &sphi[(a*6 + e)*12];
        const float s0 = kdot<3>(z,0,ph), s1 = kdot<3>(z,1,ph), s2 = kdot<3>(z,2,ph);
        const float q0 = ph[8], q1 = ph[9], q2 = ph[10];
        const float c0 = q1*s2 - q2*s1;
        const float c1 = q2*s0 - q0*s2;
        const float c2 = q0*s1 - q1*s0;
        float* pb = &psis[((a*6 + e)*128 + tl)*9];
        pb[0] += c0*q0; pb[1] += c0*q1; pb[2] += c0*q2;
        pb[3] += c1*q0; pb[4] += c1*q1; pb[5] += c1*q2;
        pb[6] += c2*q0; pb[7] += c2*q1; pb[8] += c2*q2;
      }
    }
#pragma unroll
    for (int e = 0; e < 6; ++e) {
      if (b0 + e < da) {
        const float* pb = &psis[((a*6 + e)*128 + tl)*9];
        unsigned short* bp = &psiD[(size_t)(offa + b0 + e)*1152 + tl*9];
#pragma unroll
        for (int j = 0; j < 9; ++j) bp[j] = f2bf(pb[j]);
      }
    }
  }
}

// ---------------------------------------------------------------------------
// Scalar MLP, 32 combos/block, in-place rewrite of psiA. 256 thr.
// ---------------------------------------------------------------------------
__global__ __launch_bounds__(256, 2) void mlp_a_kernel(
    unsigned short* __restrict__ psiA,
    const float* __restrict__ Wd_a,
    const float* __restrict__ W1, const float* __restrict__ b1,
    const float* __restrict__ W2, const float* __restrict__ b2,
    const float* __restrict__ W3, const float* __restrict__ b3)
{
  __shared__ float PA[32*128];   // 16 KB
  __shared__ float H1[32*256];   // 32 KB
  __shared__ float H2[32*256];   // 32 KB  -> exactly 80 KB
  const int t = threadIdx.x;
  const int cbase = blockIdx.x * 32;

  for (int q = t; q < 4096; q += 256)
    PA[q] = bf2f(psiA[(size_t)cbase*128 + q]);
  __syncthreads();
  { // h1 = lrelu(W1 x + b1): 64 pgroups(4 rows) x 4 jgroups(8 combos)
    const int p0 = (t & 63) * 4, j0 = (t >> 6) * 8;
    float acc[4][8];
#pragma unroll
    for (int r = 0; r < 4; ++r)
#pragma unroll
      for (int j = 0; j < 8; ++j) acc[r][j] = 0.f;
    for (int c = 0; c < 128; c += 4) {
      float4 w0 = *(const float4*)&W1[(size_t)(p0+0)*128 + c];
      float4 w1 = *(const float4*)&W1[(size_t)(p0+1)*128 + c];
      float4 w2 = *(const float4*)&W1[(size_t)(p0+2)*128 + c];
      float4 w3 = *(const float4*)&W1[(size_t)(p0+3)*128 + c];
#pragma unroll
      for (int j = 0; j < 8; ++j) {
        const float4 x = *(const float4*)&PA[(j0+j)*128 + c];
        acc[0][j] += dot4f(w0, x); acc[1][j] += dot4f(w1, x);
        acc[2][j] += dot4f(w2, x); acc[3][j] += dot4f(w3, x);
      }
    }
    const float bb0 = b1[p0], bb1 = b1[p0+1], bb2 = b1[p0+2], bb3 = b1[p0+3];
#pragma unroll
    for (int j = 0; j < 8; ++j) {
      float4 v; v.x = lrelu(acc[0][j]+bb0); v.y = lrelu(acc[1][j]+bb1);
      v.z = lrelu(acc[2][j]+bb2); v.w = lrelu(acc[3][j]+bb3);
      *(float4*)&H1[(j0+j)*256 + p0] = v;
    }
  }
  __syncthreads();
  { // h2 = lrelu(W2 h1 + b2)
    const int p0 = (t & 63) * 4, j0 = (t >> 6) * 8;
    float acc[4][8];
#pragma unroll
    for (int r = 0; r < 4; ++r)
#pragma unroll
      for (int j = 0; j < 8; ++j) acc[r][j] = 0.f;
    for (int c = 0; c < 256; c += 4) {
      float4 w0 = *(const float4*)&W2[(size_t)(p0+0)*256 + c];
      float4 w1 = *(const float4*)&W2[(size_t)(p0+1)*256 + c];
      float4 w2 = *(const float4*)&W2[(size_t)(p0+2)*256 + c];
      float4 w3 = *(const float4*)&W2[(size_t)(p0+3)*256 + c];
#pragma unroll
      for (int j = 0; j < 8; ++j) {
        const float4 x = *(const float4*)&H1[(j0+j)*256 + c];
        acc[0][j] += dot4f(w0, x); acc[1][j] += dot4f(w1, x);
        acc[2][j] += dot4f(w2, x); acc[3][j] += dot4f(w3, x);
      }
    }
    const float bb0 = b2[p0], bb1 = b2[p0+1], bb2 = b2[p0+2], bb3 = b2[p0+3];
#pragma unroll
    for (int j = 0; j < 8; ++j) {
      float4 v; v.x = lrelu(acc[0][j]+bb0); v.y = lrelu(acc[1][j]+bb1);
      v.z = lrelu(acc[2][j]+bb2); v.w = lrelu(acc[3][j]+bb3);
      *(float4*)&H2[(j0+j)*256 + p0] = v;
    }
  }
  __syncthreads();
  { // out = x + Wd x + W3 h2 + b3 -> psiA (bf16, in place)
    const int p0 = (t & 63) * 2, j0 = (t >> 6) * 8;
    float acc[2][8];
#pragma unroll
    for (int r = 0; r < 2; ++r)
#pragma unroll
      for (int j = 0; j < 8; ++j) acc[r][j] = 0.f;
    for (int c = 0; c < 128; c += 4) {
      float4 w0 = *(const float4*)&Wd_a[(size_t)(p0+0)*128 + c];
      float4 w1 = *(const float4*)&Wd_a[(size_t)(p0+1)*128 + c];
#pragma unroll
      for (int j = 0; j < 8; ++j) {
        const float4 x = *(const float4*)&PA[(j0+j)*128 + c];
        acc[0][j] += dot4f(w0, x); acc[1][j] += dot4f(w1, x);
      }
    }
    for (int c = 0; c < 256; c += 4) {
      float4 w0 = *(const float4*)&W3[(size_t)(p0+0)*256 + c];
      float4 w1 = *(const float4*)&W3[(size_t)(p0+1)*256 + c];
#pragma unroll
      for (int j = 0; j < 8; ++j) {
        const float4 x = *(const float4*)&H2[(j0+j)*256 + c];
        acc[0][j] += dot4f(w0, x); acc[1][j] += dot4f(w1, x);
      }
    }
    const float bb0 = b3[p0], bb1 = b3[p0+1];
#pragma unroll
    for (int j = 0; j < 8; ++j) {
      const float o0 = acc[0][j] + bb0 + PA[(j0+j)*128 + p0];
      const float o1 = acc[1][j] + bb1 + PA[(j0+j)*128 + p0 + 1];
      psiA[(size_t)(cbase + j0 + j)*128 + p0]     = f2bf(o0);
      psiA[(size_t)(cbase + j0 + j)*128 + p0 + 1] = f2bf(o1);
    }
  }
}

// ---------------------------------------------------------------------------
// Vector MLP, 8 combos/block, in-place rewrite of psiV. 192 thr.
// R6 structure + padded LDS rows (PVS=296, HVS=584: 2-row bank offset = 16)
// + float4 stores of HV/HV2 (lane-stride 16B, conflict-free).
// ---------------------------------------------------------------------------
#define PVS 296
#define HVS 584
__global__ __launch_bounds__(192, 3) void mlp_v_kernel(
    unsigned short* __restrict__ psiV,
    const float* __restrict__ Vd, const float* __restrict__ V1,
    const float* __restrict__ V2, const float* __restrict__ V3)
{
  __shared__ float PV[8*PVS];    // [j][i*96 + o], padded row
  __shared__ float HV[8*HVS];    // [j][i*192 + p], padded row
  __shared__ float HV2[8*HVS];
  const int t = threadIdx.x;
  const int cbase = blockIdx.x * 8;

  for (int q = t; q < 2304; q += 192) {
    const int j = q / 288, r = q % 288, i = r / 96, o = r % 96;
    PV[j*PVS + i*96 + o] = bf2f(psiV[(size_t)(cbase + j)*288 + o*3 + i]);
  }
  __syncthreads();
  { // hv = tsig(V1 x): 48 pg(4 rows) x 4 jg(2 combos)
    const int p0 = (t % 48) * 4, j0 = (t / 48) * 2;
    float acc[4][2][3];
#pragma unroll
    for (int r = 0; r < 4; ++r)
#pragma unroll
      for (int j = 0; j < 2; ++j) { acc[r][j][0]=0.f; acc[r][j][1]=0.f; acc[r][j][2]=0.f; }
    for (int c = 0; c < 96; c += 4) {
      float4 w[4];
#pragma unroll
      for (int r = 0; r < 4; ++r) w[r] = *(const float4*)&V1[(size_t)(p0+r)*96 + c];
#pragma unroll
      for (int j = 0; j < 2; ++j)
#pragma unroll
        for (int i = 0; i < 3; ++i) {
          const float4 x = *(const float4*)&PV[(j0+j)*PVS + i*96 + c];
#pragma unroll
          for (int r = 0; r < 4; ++r) acc[r][j][i] += dot4f(w[r], x);
        }
    }
    float scl[4][2];
#pragma unroll
    for (int r = 0; r < 4; ++r)
#pragma unroll
      for (int j = 0; j < 2; ++j) {
        const float nn = sqrtf(acc[r][j][0]*acc[r][j][0] + acc[r][j][1]*acc[r][j][1]
                             + acc[r][j][2]*acc[r][j][2] + 1e-12f);
        scl[r][j] = (2.f / (1.f + expf(-nn)) - 1.f) / nn;
      }
#pragma unroll
    for (int j = 0; j < 2; ++j)
#pragma unroll
      for (int i = 0; i < 3; ++i) {
        float4 v;
        v.x = acc[0][j][i]*scl[0][j]; v.y = acc[1][j][i]*scl[1][j];
        v.z = acc[2][j][i]*scl[2][j]; v.w = acc[3][j][i]*scl[3][j];
        *(float4*)&HV[(j0+j)*HVS + i*192 + p0] = v;
      }
  }
  __syncthreads();
  { // hv2 = tsig(V2 hv)
    const int p0 = (t % 48) * 4, j0 = (t / 48) * 2;
    float acc[4][2][3];
#pragma unroll
    for (int r = 0; r < 4; ++r)
#pragma unroll
      for (int j = 0; j < 2; ++j) { acc[r][j][0]=0.f; acc[r][j][1]=0.f; acc[r][j][2]=0.f; }
    for (int c = 0; c < 192; c += 4) {
      float4 w[4];
#pragma unroll
      for (int r = 0; r < 4; ++r) w[r] = *(const float4*)&V2[(size_t)(p0+r)*192 + c];
#pragma unroll
      for (int j = 0; j < 2; ++j)
#pragma unroll
        for (int i = 0; i < 3; ++i) {
          const float4 x = *(const float4*)&HV[(j0+j)*HVS + i*192 + c];
#pragma unroll
          for (int r = 0; r < 4; ++r) acc[r][j][i] += dot4f(w[r], x);
        }
    }
    float scl[4][2];
#pragma unroll
    for (int r = 0; r < 4; ++r)
#pragma unroll
      for (int j = 0; j < 2; ++j) {
        const float nn = sqrtf(acc[r][j][0]*acc[r][j][0] + acc[r][j][1]*acc[r][j][1]
                             + acc[r][j][2]*acc[r][j][2] + 1e-12f);
        scl[r][j] = (2.f / (1.f + expf(-nn)) - 1.f) / nn;
      }
#pragma unroll
    for (int j = 0; j < 2; ++j)
#pragma unroll
      for (int i = 0; i < 3; ++i) {
        float4 v;
        v.x = acc[0][j][i]*scl[0][j]; v.y = acc[1][j][i]*scl[1][j];
        v.z = acc[2][j][i]*scl[2][j]; v.w = acc[3][j][i]*scl[3][j];
        *(float4*)&HV2[(j0+j)*HVS + i*192 + p0] = v;
      }
  }
  __syncthreads();
  { // out = x + Vd x + V3 hv2 -> psiV (bf16, in place): 48 pg(2 rows) x 4 jg(2 combos)
    const int p0 = (t % 48) * 2, j0 = (t / 48) * 2;
    float acc[2][2][3];
#pragma unroll
    for (int r = 0; r < 2; ++r)
#pragma unroll
      for (int j = 0; j < 2; ++j) { acc[r][j][0]=0.f; acc[r][j][1]=0.f; acc[r][j][2]=0.f; }
    for (int c = 0; c < 96; c += 4) {
      float4 w0 = *(const float4*)&Vd[(size_t)(p0+0)*96 + c];
      float4 w1 = *(const float4*)&Vd[(size_t)(p0+1)*96 + c];
#pragma unroll
      for (int j = 0; j < 2; ++j)
#pragma unroll
        for (int i = 0; i < 3; ++i) {
          const float4 x = *(const float4*)&PV[(j0+j)*PVS + i*96 + c];
          acc[0][j][i] += dot4f(w0, x); acc[1][j][i] += dot4f(w1, x);
        }
    }
    for (int c = 0; c < 192; c += 4) {
      float4 w0 = *(const float4*)&V3[(size_t)(p0+0)*192 + c];
      float4 w1 = *(const float4*)&V3[(size_t)(p0+1)*192 + c];
#pragma unroll
      for (int j = 0; j < 2; ++j)
#pragma unroll
        for (int i = 0; i < 3; ++i) {
          const float4 x = *(const float4*)&HV2[(j0+j)*HVS + i*192 + c];
          acc[0][j][i] += dot4f(w0, x); acc[1][j][i] += dot4f(w1, x);
        }
    }
#pragma unroll
    for (int r = 0; r < 2; ++r)
#pragma unroll
      for (int j = 0; j < 2; ++j)
#pragma unroll
        for (int i = 0; i < 3; ++i) {
          const float v = acc[r][j][i] + PV[(j0+j)*PVS + i*96 + p0 + r];
          psiV[(size_t)(cbase + j0 + j)*288 + (p0 + r)*3 + i] = f2bf(v);
        }
  }
}

// ---------------------------------------------------------------------------
// Gather (by src) + fused output projection. Block per src atom, 256 thr.
// ---------------------------------------------------------------------------
__global__ __launch_bounds__(256, 2) void gather_out_kernel(
    const int* __restrict__ soff, const int* __restrict__ sperm,
    const unsigned short* __restrict__ psiA, const unsigned short* __restrict__ psiV,
    const unsigned short* __restrict__ psiD,
    const float* __restrict__ Wa, const float* __restrict__ Wv, const float* __restrict__ Wd,
    float* __restrict__ out)
{
  __shared__ float bs[1984];
  const int n = blockIdx.x, t = threadIdx.x;
  const int s0 = soff[n], s1 = soff[n + 1];
  float acc[8];
#pragma unroll
  for (int u = 0; u < 8; ++u) acc[u] = 0.f;
  for (int p2 = s0; p2 < s1; ++p2) {
    const int slot = sperm[p2];
    const unsigned short* ra = psiA + (size_t)slot * 256;
    const unsigned short* rv = psiV + (size_t)slot * 576;
    const unsigned short* rd = psiD + (size_t)slot * 1152;
#pragma unroll
    for (int u = 0; u < 8; ++u) {
      const int v = t + 256 * u;
      if (v < 256)        acc[u] += bf2f(ra[v]);
      else if (v < 832)   acc[u] += bf2f(rv[v - 256]);
      else if (v < 1984)  acc[u] += bf2f(rd[v - 832]);
    }
  }
#pragma unroll
  for (int u = 0; u < 8; ++u) {
    const int v = t + 256 * u;
    if (v < 1984) bs[v] = acc[u];
  }
  __syncthreads();
  if (t < 128) {
    const float* W = &Wa[(size_t)t * 256];
    float a = 0.f;
    for (int c = 0; c < 256; c += 4) a += dot4f(*(const float4*)&W[c], *(const float4*)&bs[c]);
    out[(size_t)n*128 + t] = a;
  }
  if (t < 96) {
    const float* W = &Wv[(size_t)t * 192];
    float a0 = 0.f, a1 = 0.f, a2 = 0.f;
    for (int c = 0; c < 192; ++c) {
      const float w = W[c]; const float* x = &bs[256 + c*3];
      a0 = fmaf(w, x[0], a0); a1 = fmaf(w, x[1], a1); a2 = fmaf(w, x[2], a2);
    }
    float* d = &out[OUT_V + ((size_t)n*96 + t)*3];
    d[0] = a0; d[1] = a1; d[2] = a2;
  }
  if (t < 64) {
    const float* W = &Wd[(size_t)t * 128];
    float a[9] = {0,0,0,0,0,0,0,0,0};
    for (int c = 0; c < 128; ++c) {
      const float w = W[c]; const float* x = &bs[832 + c*9];
#pragma unroll
      for (int j = 0; j < 9; ++j) a[j] = fmaf(w, x[j], a[j]);
    }
    float* d = &out[OUT_D + ((size_t)n*64 + t)*9];
#pragma unroll
    for (int j = 0; j < 9; ++j) d[j] = a[j];
  }
}

// ---------------------------------------------------------------------------
// Host entry
// ---------------------------------------------------------------------------
extern "C" void kernel_launch(void* const* d_in, const int* in_sizes, int n_in,
                              void* d_out, int out_size, void* d_ws, size_t ws_size,
                              hipStream_t stream) {
  (void)in_sizes; (void)n_in; (void)out_size; (void)ws_size;
  const int*   src  = (const int*)d_in[0];
  const int*   dst  = (const int*)d_in[1];
  const float* r_ij = (const float*)d_in[2];
  const float* x_a  = (const float*)d_in[3];
  const float* x_v  = (const float*)d_in[4];
  const float* x_d  = (const float*)d_in[5];
  const float* P[13];
  for (int i = 0; i < 13; ++i) P[i] = (const float*)d_in[6 + i];
  const float* W_in_a  = (const float*)d_in[19];
  const float* W_in_v  = (const float*)d_in[20];
  const float* W_in_d  = (const float*)d_in[21];
  const float* W_out_a = (const float*)d_in[22];
  const float* W_out_v = (const float*)d_in[23];
  const float* W_out_d = (const float*)d_in[24];
  const float* Wd_a = (const float*)d_in[25];
  const float* W1   = (const float*)d_in[26];
  const float* b1   = (const float*)d_in[27];
  const float* W2   = (const float*)d_in[28];
  const float* b2   = (const float*)d_in[29];
  const float* W3   = (const float*)d_in[30];
  const float* b3   = (const float*)d_in[31];
  const float* Vd   = (const float*)d_in[32];
  const float* V1   = (const float*)d_in[33];
  const float* V2   = (const float*)d_in[34];
  const float* V3   = (const float*)d_in[35];

  float* ws = (float*)d_ws;
  float* Pt = ws;
  int*   ib = (int*)(ws + INT_OFF);
  unsigned short* psiA = (unsigned short*)(ws + PSIA_OFF);
  unsigned short* psiV = (unsigned short*)(ws + PSIV_OFF);
  unsigned short* psiD = (unsigned short*)(ws + PSID_OFF);

  // 1) transpose P tensors to [C][O][8]
  static const int Od[13] = {128,128,128, 96, 96, 96, 96, 96, 64, 64, 64, 64, 64};
  static const int Cd[13] = {128, 96, 64, 96,128, 64, 96, 96, 64,128, 96, 64, 96};
  for (int i = 0; i < 13; ++i) {
    const int total = Od[i] * Cd[i];
    transposeP_kernel<<<(total + 255) / 256, 256, 0, stream>>>(P[i], Pt + POFF[i], Od[i], Cd[i]);
  }

  // 2) zero sort counters
  hipMemsetAsync(ib, 0, 20000 * sizeof(int), stream);

  // 3) dst-sort + src-sort + per-edge encodings
  const int egrid = (NE + 255) / 256;
  hist_kernel<<<egrid, 256, 0, stream>>>(dst, ib + ICNT);
  scan_kernel<<<1, 256, 0, stream>>>(ib + ICNT, ib + IOFF);
  sort_scatter_kernel<<<egrid, 256, 0, stream>>>(dst, ib + IOFF, ib + ICUR, ib + IEIDX, ib + ISLOT);
  hist_kernel<<<egrid, 256, 0, stream>>>(src, ib + SCNT);
  scan_kernel<<<1, 256, 0, stream>>>(ib + SCNT, ib + SOFF);
  ssort_kernel<<<egrid, 256, 0, stream>>>(src, ib + ISLOT, ib + SOFF, ib + SCUR, ib + SPERM);
  phi_kernel<<<egrid, 256, 0, stream>>>(ib + IEIDX, r_ij, ws + PHI_OFF);

  // 4) input projections
  proj_in_kernel<<<NA, 256, 0, stream>>>(x_a, x_v, x_d, W_in_a, W_in_v, W_in_d,
                                         ws + A_OFF, ws + V_OFF, ws + D_OFF);

  // 5) messages: rank-specialized passes, block per atom pair, LDS psi
  pass_a_kernel<<<NA/2, 256, 0, stream>>>(ib + IOFF, ws + PHI_OFF, Pt,
                                          ws + A_OFF, ws + V_OFF, ws + D_OFF, psiA);
  pass_v_kernel<<<NA/2, 192, 0, stream>>>(ib + IOFF, ws + PHI_OFF, Pt,
                                          ws + A_OFF, ws + V_OFF, ws + D_OFF, psiV);
  pass_d_kernel<<<NA/2, 256, 0, stream>>>(ib + IOFF, ws + PHI_OFF, Pt,
                                          ws + A_OFF, ws + V_OFF, ws + D_OFF, psiD);

  // 6) edge MLPs (in place).  Combo counts are 2*NE for BOTH.
  mlp_a_kernel<<<(2*NE)/32, 256, 0, stream>>>(psiA, Wd_a, W1, b1, W2, b2, W3, b3);
  mlp_v_kernel<<<(2*NE)/8, 192, 0, stream>>>(psiV, Vd, V1, V2, V3);

  // 7) gather by src + fused output projection
  gather_out_kernel<<<NA, 256, 0, stream>>>(ib + SOFF, ib + SPERM,
                                            psiA, psiV, psiD,
                                            W_out_a, W_out_v, W_out_d, (float*)d_out);
}